// Round 10
// baseline (291.021 us; speedup 1.0000x reference)
//
#include <hip/hip_runtime.h>
#include <hip/hip_bf16.h>

// Simple_6270652252303. Inputs float32 (detector-verified; bf16 path kept).
// Key math: sA is a constant matrix (A[d,n] == a). Then
//   y[b,t,d] = E_t[d] * sum_{s<=t} G_b[t,s] * dx_s[d]/E_s[d],
//   E_t = exp(a*cumsum(delta)),  G_b = tril((T2@M33)@T2^T + rank-1 terms),
//   M33 = sW3 @ sW2^T.
// Fast path (A uniform, runtime-verified): k_prep -> k_A -> k_G -> k_Y.
// Fallback (A non-uniform): gated k_B + k_scan (R9 versions).
//   k_prep: M33, u=W3@b2, v=W2@b3, k0=b2.b3, A-uniform flags + a.
//   k_A:    text -> LN -> LN -> t2g + ddx{de,de*x} + Mkv (collapsed head).
//   k_G:    per batch: Z=T2@M33; G = tril(Z@T2^T + ru+rv+k0) -> global.
//   k_Y:    per (batch, d-chunk): cumsum/exp -> V,E; Y = E * (tril(G)@V).
//   k_head: out = y @ Mkv + k.

typedef __hip_bfloat16 bf16;

#define BATCH 64
#define SEQ   63
#define ROWS  (BATCH * SEQ)   // 4032
#define DIN   100
#define H1    128
#define DM    100
#define NS    300

__device__ __forceinline__ float2 up2(unsigned u) {
    float2 r;
    r.x = __uint_as_float(u << 16);
    r.y = __uint_as_float(u & 0xffff0000u);
    return r;
}
template<bool ISB>
__device__ __forceinline__ float LD(const void* p, int i) {
    if (ISB) return __bfloat162float(((const bf16*)p)[i]);
    else     return ((const float*)p)[i];
}
template<bool ISB>
__device__ __forceinline__ float2 LD2(const void* p, int i) {   // elems 2i,2i+1
    if (ISB) return up2(((const unsigned*)p)[i]);
    else     return ((const float2*)p)[i];
}
__device__ __forceinline__ float4 waveReduceSum4(float4 v) {
#pragma unroll
    for (int off = 32; off > 0; off >>= 1) {
        const float a = __shfl_xor(v.x, off, 64);
        const float b = __shfl_xor(v.y, off, 64);
        const float c = __shfl_xor(v.z, off, 64);
        const float d = __shfl_xor(v.w, off, 64);
        v.x += a; v.y += b; v.z += c; v.w += d;
    }
    return v;
}
__device__ __forceinline__ float lrelu(float x) { return x >= 0.f ? x : 0.01f * x; }
__device__ __forceinline__ float softplusf(float x) {
    return (x > 20.f) ? x : log1pf(__expf(x));
}
__device__ __forceinline__ bool flags_uniform(const float* __restrict__ f) {
    bool u = true;
#pragma unroll
    for (int i = 0; i < 8; ++i) u &= (f[i] > 0.5f);
    return u;
}

// bf16-vs-f32 storage detector (wave-uniform ballot; no LDS, no barrier).
__device__ __forceinline__ bool detect_bf16(const unsigned short* __restrict__ probe) {
    const int l = threadIdx.x & 63;
    const unsigned u0 = probe[l * 2];
    const unsigned u1 = probe[l * 2 + 1];
    const float v0 = fabsf(__uint_as_float(u0 << 16));
    const float v1 = fabsf(__uint_as_float(u1 << 16));
    const bool big = !(v0 < 1000.f) || !(v1 < 1000.f);
    const bool zero_even = (u0 == 0u);
    const unsigned long long mb = __ballot(big);
    const unsigned long long mz = __ballot(zero_even);
    return (mb == 0ULL) && (__popcll(mz) < 32);
}

// ---------------------------------------------------------------------------
// k_prep: M33 = W3@W2^T (blocks 0..99, one d3-row each), u (block 100),
// v + k0 (block 101), A-uniformity flags + a (blocks 102..109).
// ---------------------------------------------------------------------------
template<bool ISB>
__device__ __forceinline__ void prep_impl(
    const void* __restrict__ sW2, const void* __restrict__ sb2,
    const void* __restrict__ sW3, const void* __restrict__ sb3,
    const void* __restrict__ sA,
    float* __restrict__ M33, float* __restrict__ uvec, float* __restrict__ vvec,
    float* __restrict__ k0w, float* __restrict__ Afl, float (&shm)[304])
{
    const int blk = blockIdx.x, tid = threadIdx.x;
    if (blk < 100) {
        for (int i = tid; i < 300; i += 256) shm[i] = LD<ISB>(sW3, blk * 300 + i);
        __syncthreads();
        if (tid < 100) {
            float acc = 0.f;
#pragma unroll 4
            for (int n = 0; n < 300; ++n) acc += shm[n] * LD<ISB>(sW2, tid * 300 + n);
            M33[blk * 100 + tid] = acc;          // M33[d3][d2]
        }
    } else if (blk == 100) {
        if (tid < 100) {
            float acc = 0.f;
            for (int n = 0; n < 300; ++n) acc += LD<ISB>(sW3, tid * 300 + n) * LD<ISB>(sb2, n);
            uvec[tid] = acc;
        }
    } else if (blk == 101) {
        if (tid < 100) {
            float acc = 0.f;
            for (int n = 0; n < 300; ++n) acc += LD<ISB>(sW2, tid * 300 + n) * LD<ISB>(sb3, n);
            vvec[tid] = acc;
        }
        if (tid == 128) {
            float acc = 0.f;
            for (int n = 0; n < 300; ++n) acc += LD<ISB>(sb2, n) * LD<ISB>(sb3, n);
            k0w[0] = acc;
        }
    } else {
        const int j = blk - 102;                 // 0..7, slice of 3750
        const float a0 = LD<ISB>(sA, 0);
        bool ok = true;
        for (int i = j * 3750 + tid; i < (j + 1) * 3750; i += 256)
            ok &= (LD<ISB>(sA, i) == a0);
        if (tid == 0) shm[300] = 1.f;
        __syncthreads();
        if (!ok) shm[300] = 0.f;                 // benign same-value race
        __syncthreads();
        if (tid == 0) Afl[j] = shm[300];
        if (j == 0 && tid == 1) Afl[8] = a0;
    }
}

__global__ __launch_bounds__(256) void k_prep(
    const void* sW2, const void* sb2, const void* sW3, const void* sb3,
    const void* sA, float* M33, float* uvec, float* vvec, float* k0w,
    float* Afl, const unsigned short* probe)
{
    __shared__ float shm[304];
    if (detect_bf16(probe)) prep_impl<true >(sW2, sb2, sW3, sb3, sA, M33, uvec, vvec, k0w, Afl, shm);
    else                    prep_impl<false>(sW2, sb2, sW3, sb3, sA, M33, uvec, vvec, k0w, Afl, shm);
}

// ---------------------------------------------------------------------------
// k_A: GEMM1 -> LN -> GEMM2 -> LN -> t2g, + delta/ddx, + Mkv. 2 rows/wave,
// grid 504, ring-prefetched weight streams, wave-private LDS, no barriers.
// ---------------------------------------------------------------------------
template<bool ISB>
__device__ __forceinline__ void a_impl(
    const void* __restrict__ text,
    const void* __restrict__ tW1, const void* __restrict__ tb1,
    const void* __restrict__ tg1, const void* __restrict__ tbe1,
    const void* __restrict__ tW2, const void* __restrict__ tb2,
    const void* __restrict__ tg2, const void* __restrict__ tbe2,
    const void* __restrict__ sW1, const void* __restrict__ sb1,
    const void* __restrict__ cW1, const void* __restrict__ cb1,
    const void* __restrict__ cW2, const void* __restrict__ cb2,
    float* __restrict__ ddx, float* __restrict__ t2g, float* __restrict__ Mkv,
    float (&xb)[4][DIN][2], float (&t1b)[4][H1][2], float (&t2b)[4][DM][2])
{
    const int w    = threadIdx.x >> 6;
    const int lane = threadIdx.x & 63;
    const int r0   = blockIdx.x * 8 + w * 2;   // rows r0, r0+1

    if (lane < 50) {
#pragma unroll
        for (int r = 0; r < 2; ++r) {
            const float2 xv = LD2<ISB>(text, (r0 + r) * 50 + lane);
            xb[w][2 * lane][r]     = xv.x;
            xb[w][2 * lane + 1][r] = xv.y;
        }
    }
    // wave-private LDS: no barrier anywhere

    // ---- GEMM1 (100 -> 128), ring prefetch depth 10 ----
    const float2 b1v = LD2<ISB>(tb1, lane);
    float ax0 = b1v.x, ay0 = b1v.y, ax1 = b1v.x, ay1 = b1v.y;
    {
        float2 ring[10];
#pragma unroll
        for (int j = 0; j < 10; ++j) ring[j] = LD2<ISB>(tW1, j * 64 + lane);
        for (int kk = 0; kk < DIN; kk += 10) {
#pragma unroll
            for (int j = 0; j < 10; ++j) {
                const int k = kk + j;
                const float2 wv = ring[j];
                if (k + 10 < DIN) ring[j] = LD2<ISB>(tW1, (k + 10) * 64 + lane);
                const float2 xv = *(const float2*)&xb[w][k][0];
                ax0 += xv.x * wv.x; ay0 += xv.x * wv.y;
                ax1 += xv.y * wv.x; ay1 += xv.y * wv.y;
            }
        }
    }
    {   // LN(128)+LReLU, both rows via one quad-chain reduce
        float4 red = waveReduceSum4(make_float4(
            ax0 + ay0, ax0 * ax0 + ay0 * ay0,
            ax1 + ay1, ax1 * ax1 + ay1 * ay1));
        const float m0 = red.x * (1.f / 128.f);
        const float rs0 = rsqrtf(red.y * (1.f / 128.f) - m0 * m0 + 1e-5f);
        const float m1 = red.z * (1.f / 128.f);
        const float rs1 = rsqrtf(red.w * (1.f / 128.f) - m1 * m1 + 1e-5f);
        const float2 g = LD2<ISB>(tg1, lane), be = LD2<ISB>(tbe1, lane);
        float2 v;
        v.x = lrelu((ax0 - m0) * rs0 * g.x + be.x);
        v.y = lrelu((ax1 - m1) * rs1 * g.x + be.x);
        *(float2*)&t1b[w][2 * lane][0] = v;
        v.x = lrelu((ay0 - m0) * rs0 * g.y + be.y);
        v.y = lrelu((ay1 - m1) * rs1 * g.y + be.y);
        *(float2*)&t1b[w][2 * lane + 1][0] = v;
    }

    // ---- GEMM2 (128 -> 100), ring prefetch depth 8 ----
    const bool act = lane < 50;
    const int  li  = act ? lane : 0;
    const float2 b2v = LD2<ISB>(tb2, li);
    float cx0 = b2v.x, cy0 = b2v.y, cx1 = b2v.x, cy1 = b2v.y;
    {
        float2 ring[8];
#pragma unroll
        for (int j = 0; j < 8; ++j) ring[j] = LD2<ISB>(tW2, j * 50 + li);
        for (int kk = 0; kk < H1; kk += 8) {
#pragma unroll
            for (int j = 0; j < 8; ++j) {
                const int k = kk + j;
                const float2 wv = ring[j];
                if (k + 8 < H1) ring[j] = LD2<ISB>(tW2, (k + 8) * 50 + li);
                const float2 tv = *(const float2*)&t1b[w][k][0];
                cx0 += tv.x * wv.x; cy0 += tv.x * wv.y;
                cx1 += tv.y * wv.x; cy1 += tv.y * wv.y;
            }
        }
    }
    float u0x, u0y, u1x, u1y;
    {   // LN(100)+LReLU -> t2g + t2b
        float4 red = waveReduceSum4(act ? make_float4(
            cx0 + cy0, cx0 * cx0 + cy0 * cy0,
            cx1 + cy1, cx1 * cx1 + cy1 * cy1) : make_float4(0.f, 0.f, 0.f, 0.f));
        const float m0 = red.x * 0.01f;
        const float rs0 = rsqrtf(red.y * 0.01f - m0 * m0 + 1e-5f);
        const float m1 = red.z * 0.01f;
        const float rs1 = rsqrtf(red.w * 0.01f - m1 * m1 + 1e-5f);
        if (act) {
            const float2 g = LD2<ISB>(tg2, lane), be = LD2<ISB>(tbe2, lane);
            u0x = lrelu((cx0 - m0) * rs0 * g.x + be.x);
            u0y = lrelu((cy0 - m0) * rs0 * g.y + be.y);
            u1x = lrelu((cx1 - m1) * rs1 * g.x + be.x);
            u1y = lrelu((cy1 - m1) * rs1 * g.y + be.y);
            t2b[w][2 * lane][0] = u0x; t2b[w][2 * lane + 1][0] = u0y;
            t2b[w][2 * lane][1] = u1x; t2b[w][2 * lane + 1][1] = u1y;
            *(float2*)(t2g + (r0)     * DM + 2 * lane) = make_float2(u0x, u0y);
            *(float2*)(t2g + (r0 + 1) * DM + 2 * lane) = make_float2(u1x, u1y);
        }
    }

    // ---- delta (100 cols) over k<100, ring depth 10 -> ddx {de, de*t2} ----
    const float2 sbv = LD2<ISB>(sb1, li);
    float dA0x = sbv.x, dA0y = sbv.y, dA1x = sbv.x, dA1y = sbv.y;
    {
        float2 ring[10];
#pragma unroll
        for (int j = 0; j < 10; ++j) ring[j] = LD2<ISB>(sW1, j * 50 + li);
        for (int kk = 0; kk < DM; kk += 10) {
#pragma unroll
            for (int j = 0; j < 10; ++j) {
                const int k = kk + j;
                const float2 wv = ring[j];
                if (k + 10 < DM) ring[j] = LD2<ISB>(sW1, (k + 10) * 50 + li);
                const float2 tv = *(const float2*)&t2b[w][k][0];
                dA0x += tv.x * wv.x; dA0y += tv.x * wv.y;
                dA1x += tv.y * wv.x; dA1y += tv.y * wv.y;
            }
        }
    }
    if (act) {
        float de0 = softplusf(dA0x), de1 = softplusf(dA0y);
        float4 o;
        o.x = de0; o.y = de0 * u0x; o.z = de1; o.w = de1 * u0y;
        *(float4*)(ddx + (r0) * (2 * DM) + 4 * lane) = o;
        de0 = softplusf(dA1x); de1 = softplusf(dA1y);
        o.x = de0; o.y = de0 * u1x; o.z = de1; o.w = de1 * u1y;
        *(float4*)(ddx + (r0 + 1) * (2 * DM) + 4 * lane) = o;
    }

    // ---- side duty: collapsed head M = cW1@cW2, k = cb1@cW2+cb2 ----
    if (blockIdx.x == 0 && w == 0) {
#pragma unroll
        for (int t = lane; t < 200; t += 64) {
            const int d = t >> 1, j = t & 1;
            float m = 0.f;
            for (int i = 0; i < 50; ++i)
                m += LD<ISB>(cW1, d * 50 + i) * LD<ISB>(cW2, 2 * i + j);
            Mkv[t] = m;
        }
        if (lane < 2) {
            float kv = LD<ISB>(cb2, lane);
            for (int i = 0; i < 50; ++i)
                kv += LD<ISB>(cb1, i) * LD<ISB>(cW2, 2 * i + lane);
            Mkv[200 + lane] = kv;
        }
    }
}

__global__ __launch_bounds__(256, 1) void k_A(
    const void* text,
    const void* tW1, const void* tb1, const void* tg1, const void* tbe1,
    const void* tW2, const void* tb2, const void* tg2, const void* tbe2,
    const void* sW1, const void* sb1,
    const void* cW1, const void* cb1, const void* cW2, const void* cb2,
    float* ddx, float* t2g, float* Mkv, const unsigned short* probe)
{
    __shared__ __align__(16) float xb[4][DIN][2];
    __shared__ __align__(16) float t1b[4][H1][2];
    __shared__ __align__(16) float t2b[4][DM][2];
    if (detect_bf16(probe))
        a_impl<true >(text, tW1, tb1, tg1, tbe1, tW2, tb2, tg2, tbe2,
                      sW1, sb1, cW1, cb1, cW2, cb2, ddx, t2g, Mkv, xb, t1b, t2b);
    else
        a_impl<false>(text, tW1, tb1, tg1, tbe1, tW2, tb2, tg2, tbe2,
                      sW1, sb1, cW1, cb1, cW2, cb2, ddx, t2g, Mkv, xb, t1b, t2b);
}

// ---------------------------------------------------------------------------
// k_G (fast path): per batch, Z = T2@M33; G = tril(Z@T2^T + ru + rv + k0).
// ---------------------------------------------------------------------------
__global__ __launch_bounds__(256) void k_G(
    const float* __restrict__ t2g, const float* __restrict__ M33,
    const float* __restrict__ uvec, const float* __restrict__ vvec,
    const float* __restrict__ k0w, float* __restrict__ G,
    const float* __restrict__ Afl)
{
    __shared__ float sT2[64][101];
    __shared__ float sZ[64][101];
    __shared__ float ru[64], rv[64];
    if (!flags_uniform(Afl)) return;
    const int b = blockIdx.x, tid = threadIdx.x;

    for (int i = tid; i < 3150; i += 256) {
        const float2 v = *(const float2*)(t2g + b * 6300 + 2 * i);
        const int t = i / 50, k = 2 * (i % 50);
        sT2[t][k] = v.x; sT2[t][k + 1] = v.y;
    }
    __syncthreads();

    if (tid < 126) {
        const int t = (tid < 63) ? tid : tid - 63;
        const float* vec = (tid < 63) ? uvec : vvec;
        float acc = 0.f;
#pragma unroll 4
        for (int k = 0; k < 100; ++k) acc += sT2[t][k] * vec[k];
        if (tid < 63) ru[t] = acc; else rv[t] = acc;
    }
    for (int o = tid; o < 1575; o += 256) {
        const int t = o / 25, i4 = o % 25;
        float4 acc = make_float4(0.f, 0.f, 0.f, 0.f);
#pragma unroll 2
        for (int k = 0; k < 100; ++k) {
            const float tv = sT2[t][k];
            const float4 m = *(const float4*)(M33 + k * 100 + 4 * i4);
            acc.x += tv * m.x; acc.y += tv * m.y;
            acc.z += tv * m.z; acc.w += tv * m.w;
        }
        sZ[t][4 * i4]     = acc.x; sZ[t][4 * i4 + 1] = acc.y;
        sZ[t][4 * i4 + 2] = acc.z; sZ[t][4 * i4 + 3] = acc.w;
    }
    __syncthreads();

    const float kz = k0w[0];
    for (int o = tid; o < 3969; o += 256) {
        const int t = o / 63, s = o % 63;
        float g = 0.f;
        if (s <= t) {
            float acc = kz + ru[t] + rv[s];
#pragma unroll 4
            for (int k = 0; k < 100; ++k) acc += sZ[t][k] * sT2[s][k];
            g = acc;
        }
        G[b * 3969 + o] = g;
    }
}

// ---------------------------------------------------------------------------
// k_Y (fast path): per (batch, 25-d chunk): E = exp(a cumsum de), V = dx/E,
// Y[t,d] = E[t,d] * sum_{s<=t} G[t,s] V[s,d].
// ---------------------------------------------------------------------------
__global__ __launch_bounds__(256) void k_Y(
    const float* __restrict__ ddx, const float* __restrict__ G,
    float* __restrict__ y, const float* __restrict__ Afl)
{
    __shared__ float sG[3969];
    __shared__ float sDE[63][25], sDX[63][25], sV[63][25], sE[63][25];
    if (!flags_uniform(Afl)) return;
    const float a = Afl[8];
    const int b = blockIdx.x >> 2, c = blockIdx.x & 3;
    const int dbase = 25 * c;
    const int tid = threadIdx.x;

    for (int i = tid; i < 3969; i += 256) sG[i] = G[b * 3969 + i];
    for (int i = tid; i < 1575; i += 256) {
        const int t = i / 25, dd = i % 25;
        const float2 v = *(const float2*)(ddx + (b * SEQ + t) * 200 + 2 * (dbase + dd));
        sDE[t][dd] = v.x; sDX[t][dd] = v.y;
    }
    __syncthreads();
    if (tid < 25) {
        float D = 0.f;
        for (int t = 0; t < SEQ; ++t) {
            D += sDE[t][tid];
            const float E = __expf(a * D);
            sE[t][tid] = E;
            sV[t][tid] = sDX[t][tid] / E;
        }
    }
    __syncthreads();
    for (int o = tid; o < 1575; o += 256) {
        const int t = o / 25, dd = o % 25;
        float acc = 0.f;
        for (int s = 0; s <= t; ++s) acc += sG[t * 63 + s] * sV[s][dd];
        y[(b * SEQ + t) * DM + dbase + dd] = sE[t][dd] * acc;
    }
}

// ---------------------------------------------------------------------------
// k_B (fallback, gated on non-uniform A): R9 BC GEMM.
// ---------------------------------------------------------------------------
template<bool ISB>
__device__ __forceinline__ float4 LD4(const void* p, int i) {
    if (ISB) {
        const uint2 u = ((const uint2*)p)[i];
        float4 r;
        r.x = __uint_as_float(u.x << 16);
        r.y = __uint_as_float(u.x & 0xffff0000u);
        r.z = __uint_as_float(u.y << 16);
        r.w = __uint_as_float(u.y & 0xffff0000u);
        return r;
    } else return ((const float4*)p)[i];
}

template<bool ISB>
__device__ __forceinline__ void b_impl(
    const float* __restrict__ t2g,
    const void* __restrict__ sW2, const void* __restrict__ sb2,
    const void* __restrict__ sW3, const void* __restrict__ sb3,
    float* __restrict__ BC, float (&sT)[DM][8])
{
    const int t  = threadIdx.x;
    const int r0 = blockIdx.x * 8;

    if (t < DM) {
#pragma unroll
        for (int r = 0; r < 8; ++r) sT[t][r] = t2g[(r0 + r) * DM + t];
    }
    __syncthreads();

    const bool isB = t < 75;
    const bool valid = t < 150;
    const int colbase = isB ? 4 * t : (valid ? 4 * (t - 75) : 0);
    const void* Wp   = isB ? sW2 : sW3;
    const void* bias = isB ? sb2 : sb3;
    const int rs4 = NS >> 2;
    const int cb4 = colbase >> 2;

    float4 acc[8];
    {
        const float4 bv = LD4<ISB>(bias, cb4);
#pragma unroll
        for (int r = 0; r < 8; ++r) acc[r] = bv;
    }
    float4 ring[4];
#pragma unroll
    for (int j = 0; j < 4; ++j) ring[j] = LD4<ISB>(Wp, j * rs4 + cb4);
    for (int kk = 0; kk < DM; kk += 4) {
#pragma unroll
        for (int j = 0; j < 4; ++j) {
            const int k = kk + j;
            const float4 wv = ring[j];
            if (k + 4 < DM) ring[j] = LD4<ISB>(Wp, (k + 4) * rs4 + cb4);
            const float4 lo = *(const float4*)&sT[k][0];
            const float4 hi = *(const float4*)&sT[k][4];
            acc[0].x += lo.x * wv.x; acc[0].y += lo.x * wv.y; acc[0].z += lo.x * wv.z; acc[0].w += lo.x * wv.w;
            acc[1].x += lo.y * wv.x; acc[1].y += lo.y * wv.y; acc[1].z += lo.y * wv.z; acc[1].w += lo.y * wv.w;
            acc[2].x += lo.z * wv.x; acc[2].y += lo.z * wv.y; acc[2].z += lo.z * wv.z; acc[2].w += lo.z * wv.w;
            acc[3].x += lo.w * wv.x; acc[3].y += lo.w * wv.y; acc[3].z += lo.w * wv.z; acc[3].w += lo.w * wv.w;
            acc[4].x += hi.x * wv.x; acc[4].y += hi.x * wv.y; acc[4].z += hi.x * wv.z; acc[4].w += hi.x * wv.w;
            acc[5].x += hi.y * wv.x; acc[5].y += hi.y * wv.y; acc[5].z += hi.y * wv.z; acc[5].w += hi.y * wv.w;
            acc[6].x += hi.z * wv.x; acc[6].y += hi.z * wv.y; acc[6].z += hi.z * wv.z; acc[6].w += hi.z * wv.w;
            acc[7].x += hi.w * wv.x; acc[7].y += hi.w * wv.y; acc[7].z += hi.w * wv.z; acc[7].w += hi.w * wv.w;
        }
    }
    if (valid) {
        const int off = isB ? 0 : 1;
#pragma unroll
        for (int r = 0; r < 8; ++r) {
            float* bp = BC + (r0 + r) * (2 * NS) + 2 * colbase + off;
            bp[0] = acc[r].x; bp[2] = acc[r].y;
            bp[4] = acc[r].z; bp[6] = acc[r].w;
        }
    }
}

__global__ __launch_bounds__(192, 1) void k_B(
    const float* t2g, const void* sW2, const void* sb2,
    const void* sW3, const void* sb3, float* BC,
    const float* Afl, const unsigned short* probe)
{
    __shared__ __align__(16) float sT[DM][8];
    if (flags_uniform(Afl)) return;      // fast path active -> skip
    if (detect_bf16(probe)) b_impl<true >(t2g, sW2, sb2, sW3, sb3, BC, sT);
    else                    b_impl<false>(t2g, sW2, sb2, sW3, sb3, BC, sT);
}

// ---------------------------------------------------------------------------
// k_scan (fallback, gated): R9 chunked-parallel-reduction scan.
// ---------------------------------------------------------------------------
template<bool ISB>
__device__ __forceinline__ void scan_impl(
    const float* __restrict__ ddx, const float* __restrict__ BC,
    const void* __restrict__ sA, float* __restrict__ y,
    float (&sacc)[4][16][2][68])
{
    const int w    = threadIdx.x >> 6;
    const int lane = threadIdx.x & 63;
    const int wid  = blockIdx.x * 4 + w;
    const int b    = wid / 50;
    const int dp   = wid % 50;
    const int d0   = 2 * dp, d1 = d0 + 1;

    int nc[5]; bool nv[5];
    float A0[5], A1[5], h0[5], h1[5];
#pragma unroll
    for (int c = 0; c < 5; ++c) {
        const int n = lane + 64 * c;
        nv[c] = n < NS;
        nc[c] = nv[c] ? n : 0;
        A0[c] = nv[c] ? LD<ISB>(sA, d0 * NS + nc[c]) : 0.f;
        A1[c] = nv[c] ? LD<ISB>(sA, d1 * NS + nc[c]) : 0.f;
        h0[c] = 0.f; h1[c] = 0.f;
    }
    const float* ddp = ddx + (b * SEQ) * (2 * DM) + 4 * dp;
    const float* BCp = BC  + (b * SEQ) * (2 * NS);
    float*       yp  = y   + (b * SEQ) * DM + d0;

    float4 pdd[3];
    float2 pbc[3][5];
#pragma unroll
    for (int j = 0; j < 3; ++j) {
        pdd[j] = *(const float4*)(ddp + j * (2 * DM));
#pragma unroll
        for (int c = 0; c < 5; ++c)
            pbc[j][c] = nv[c] ? *(const float2*)(BCp + j * (2 * NS) + 2 * nc[c])
                              : make_float2(0.f, 0.f);
    }
    const int pr = lane >> 1;
    const int hh = lane & 1;
    const int sa = pr & 15;
    const int aa = pr >> 4;

#pragma unroll 3
    for (int l = 0; l < SEQ; ++l) {
        const int bi = l % 3;
        const float4 dd = pdd[bi];
        float2 bc[5];
#pragma unroll
        for (int c = 0; c < 5; ++c) bc[c] = pbc[bi][c];
        if (l + 3 < SEQ) {
            pdd[bi] = *(const float4*)(ddp + (l + 3) * (2 * DM));
#pragma unroll
            for (int c = 0; c < 5; ++c)
                pbc[bi][c] = nv[c] ? *(const float2*)(BCp + (l + 3) * (2 * NS) + 2 * nc[c])
                                   : make_float2(0.f, 0.f);
        }
        float a0 = 0.f, a1 = 0.f;
#pragma unroll
        for (int c = 0; c < 5; ++c) {
            h0[c] = __expf(dd.x * A0[c]) * h0[c] + dd.y * bc[c].x;
            a0 += bc[c].y * h0[c];
            h1[c] = __expf(dd.z * A1[c]) * h1[c] + dd.w * bc[c].x;
            a1 += bc[c].y * h1[c];
        }
        const int s = l & 15;
        sacc[w][s][0][lane] = a0;
        sacc[w][s][1][lane] = a1;

        if (s == 15 || l == SEQ - 1) {
            const int l0 = l & ~15;
            const int cs = l - l0 + 1;
            float sum = 0.f;
            if (sa < cs) {
                const float* rowp = &sacc[w][sa][aa][hh * 32];
#pragma unroll
                for (int i = 0; i < 8; ++i) {
                    const float4 v = *(const float4*)(rowp + 4 * i);
                    sum += v.x + v.y + v.z + v.w;
                }
            }
            sum += __shfl_xor(sum, 1, 64);
            if (hh == 0 && sa < cs) yp[(l0 + sa) * DM + aa] = sum;
        }
    }
}

__global__ __launch_bounds__(256) void k_scan(
    const float* ddx, const float* BC, const void* sA, float* y,
    const float* Afl, const unsigned short* probe)
{
    __shared__ __align__(16) float sacc[4][16][2][68];
    if (flags_uniform(Afl)) return;      // fast path active -> skip
    if (detect_bf16(probe)) scan_impl<true >(ddx, BC, sA, y, sacc);
    else                    scan_impl<false>(ddx, BC, sA, y, sacc);
}

// ---------------------------------------------------------------------------
// k_head: out[row] = y[row] @ M + k. Thread per row.
// ---------------------------------------------------------------------------
template<bool ISB>
__device__ __forceinline__ void head_impl(
    const float* __restrict__ y, const float* __restrict__ Mkv,
    void* __restrict__ outp)
{
    const int row = blockIdx.x * 256 + threadIdx.x;
    if (row >= ROWS) return;
    float a0 = Mkv[200], a1 = Mkv[201];
    const float* yr = y + row * DM;
#pragma unroll 4
    for (int k = 0; k < DM; ++k) {
        const float v = yr[k];
        const float2 m = *(const float2*)(Mkv + 2 * k);
        a0 += v * m.x;
        a1 += v * m.y;
    }
    if (ISB) {
        ((bf16*)outp)[row * 2 + 0] = __float2bfloat16(a0);
        ((bf16*)outp)[row * 2 + 1] = __float2bfloat16(a1);
    } else {
        *(float2*)((float*)outp + row * 2) = make_float2(a0, a1);
    }
}

__global__ __launch_bounds__(256) void k_head(
    const float* y, const float* Mkv, void* outp, const unsigned short* probe)
{
    if (detect_bf16(probe)) head_impl<true >(y, Mkv, outp);
    else                    head_impl<false>(y, Mkv, outp);
}

// ---------------------------------------------------------------------------
extern "C" void kernel_launch(void* const* d_in, const int* in_sizes, int n_in,
                              void* d_out, int out_size, void* d_ws, size_t ws_size,
                              hipStream_t stream)
{
    const void* text = d_in[0];
    const void* tW1  = d_in[3];
    const void* tb1  = d_in[4];
    const void* tg1  = d_in[5];
    const void* tbe1 = d_in[6];
    const void* tW2  = d_in[7];
    const void* tb2  = d_in[8];
    const void* tg2  = d_in[9];
    const void* tbe2 = d_in[10];
    const void* sW1  = d_in[11];
    const void* sb1  = d_in[12];
    const void* sW2  = d_in[13];
    const void* sb2  = d_in[14];
    const void* sW3  = d_in[15];
    const void* sb3  = d_in[16];
    const void* sA   = d_in[17];
    const void* cW1  = d_in[34];
    const void* cb1  = d_in[35];
    const void* cW2  = d_in[36];
    const void* cb2  = d_in[37];
    const unsigned short* probe = (const unsigned short*)d_in[3];

    float* ws   = (float*)d_ws;
    float* ddx  = ws;                         // ROWS*200 = 806400
    float* BCv  = ddx + ROWS * 2 * DM;        // ROWS*600 (fallback BC)
    float* Gv   = BCv;                        // alias: 64*3969 (fast-path G)
    float* yv   = BCv + ROWS * 2 * NS;        // ROWS*100 (t2g, then y)
    float* Mkv  = yv + ROWS * DM;             // 202
    float* M33  = Mkv + 202;                  // 10000
    float* uvec = M33 + 10000;                // 100
    float* vvec = uvec + 100;                 // 100
    float* k0w  = vvec + 100;                 // 1
    float* Afl  = k0w + 1;                    // 9 (8 flags + a)
    float* t2g  = yv;                         // alias: t2 consumed before y write

    k_prep<<<110, 256, 0, stream>>>(sW2, sb2, sW3, sb3, sA,
                                    M33, uvec, vvec, k0w, Afl, probe);

    k_A<<<ROWS / 8, 256, 0, stream>>>(
        text, tW1, tb1, tg1, tbe1, tW2, tb2, tg2, tbe2,
        sW1, sb1, cW1, cb1, cW2, cb2, ddx, t2g, Mkv, probe);

    k_B<<<ROWS / 8, 192, 0, stream>>>(t2g, sW2, sb2, sW3, sb3, BCv, Afl, probe);

    k_G<<<BATCH, 256, 0, stream>>>(t2g, M33, uvec, vvec, k0w, Gv, Afl);

    k_Y<<<BATCH * 4, 256, 0, stream>>>(ddx, Gv, yv, Afl);

    k_scan<<<3200 / 4, 256, 0, stream>>>(ddx, BCv, sA, yv, Afl, probe);

    k_head<<<(ROWS + 255) / 256, 256, 0, stream>>>(yv, Mkv, d_out, probe);
}

// Round 11
// 223.675 us; speedup vs baseline: 1.3011x; 1.3011x over previous
//
#include <hip/hip_runtime.h>
#include <hip/hip_bf16.h>

// Simple_6270652252303. Inputs float32 (detector-verified; bf16 path kept).
// sA is constant (A[d,n]==a, runtime-verified) =>
//   y[b,t,d] = E_t[d] * sum_{s<=t} G_b[t,s] * dx_s[d]/E_s[d]
//   E_t = exp(a*cumsum(delta)),  G_b[t,s] = Z_t . T2_s + ru_t + rv_s + k0
//   Z = T2 @ M33, M33[i][j] = sum_n W3[i,n]W2[j,n], u=W3@b2, v=W2@b3, k0=b2.b3
// M33 stored padded 102-wide with col100=u, col101=v so Z picks up ru,rv free.
// Fast path: k_prep -> k_A -> k_G(256 blocks) -> k_Y(256 blocks) -> k_head.
// Fallback (A non-uniform): gated k_B + k_scan (R9 versions).

typedef __hip_bfloat16 bf16;

#define BATCH 64
#define SEQ   63
#define ROWS  (BATCH * SEQ)   // 4032
#define DIN   100
#define H1    128
#define DM    100
#define NS    300

__device__ __forceinline__ float2 up2(unsigned u) {
    float2 r;
    r.x = __uint_as_float(u << 16);
    r.y = __uint_as_float(u & 0xffff0000u);
    return r;
}
template<bool ISB>
__device__ __forceinline__ float LD(const void* p, int i) {
    if (ISB) return __bfloat162float(((const bf16*)p)[i]);
    else     return ((const float*)p)[i];
}
template<bool ISB>
__device__ __forceinline__ float2 LD2(const void* p, int i) {   // elems 2i,2i+1
    if (ISB) return up2(((const unsigned*)p)[i]);
    else     return ((const float2*)p)[i];
}
__device__ __forceinline__ float waveReduceSum(float v) {
#pragma unroll
    for (int off = 32; off > 0; off >>= 1) v += __shfl_xor(v, off, 64);
    return v;
}
__device__ __forceinline__ float4 waveReduceSum4(float4 v) {
#pragma unroll
    for (int off = 32; off > 0; off >>= 1) {
        const float a = __shfl_xor(v.x, off, 64);
        const float b = __shfl_xor(v.y, off, 64);
        const float c = __shfl_xor(v.z, off, 64);
        const float d = __shfl_xor(v.w, off, 64);
        v.x += a; v.y += b; v.z += c; v.w += d;
    }
    return v;
}
__device__ __forceinline__ float lrelu(float x) { return x >= 0.f ? x : 0.01f * x; }
__device__ __forceinline__ float softplusf(float x) {
    return (x > 20.f) ? x : log1pf(__expf(x));
}
__device__ __forceinline__ bool flags_uniform(const float* __restrict__ f) {
    bool u = true;
#pragma unroll
    for (int i = 0; i < 8; ++i) u &= (f[i] > 0.5f);
    return u;
}
__device__ __forceinline__ bool detect_bf16(const unsigned short* __restrict__ probe) {
    const int l = threadIdx.x & 63;
    const unsigned u0 = probe[l * 2];
    const unsigned u1 = probe[l * 2 + 1];
    const float v0 = fabsf(__uint_as_float(u0 << 16));
    const float v1 = fabsf(__uint_as_float(u1 << 16));
    const bool big = !(v0 < 1000.f) || !(v1 < 1000.f);
    const bool zero_even = (u0 == 0u);
    const unsigned long long mb = __ballot(big);
    const unsigned long long mz = __ballot(zero_even);
    return (mb == 0ULL) && (__popcll(mz) < 32);
}

// ---------------------------------------------------------------------------
// k_prep v2: blocks 0..99 -> M33p row d3 (102 cols: [0..99]=M33, 100=u, 101=v)
// via wave-parallel coalesced reduces; blocks 100..107 -> A-uniformity check.
// ---------------------------------------------------------------------------
template<bool ISB>
__device__ __forceinline__ void prep_impl(
    const void* __restrict__ sW2, const void* __restrict__ sb2,
    const void* __restrict__ sW3, const void* __restrict__ sb3,
    const void* __restrict__ sA,
    float* __restrict__ M33p, float* __restrict__ k0w, float* __restrict__ Afl,
    float (&sW3row)[300], float (&sb2v)[300], float (&sb3v)[304])
{
    const int blk = blockIdx.x, tid = threadIdx.x;
    const int w = tid >> 6, lane = tid & 63;
    if (blk < 100) {
        const int d3 = blk;
        for (int i = tid; i < 300; i += 256) {
            sW3row[i] = LD<ISB>(sW3, d3 * 300 + i);
            sb2v[i]   = LD<ISB>(sb2, i);
            sb3v[i]   = LD<ISB>(sb3, i);
        }
        __syncthreads();
        // 25 d2-rows per wave: M33[d3][d2] = sum_n W3row[n] * W2[d2][n]
        for (int i = 0; i < 25; ++i) {
            const int d2 = w + 4 * i;
            float acc = 0.f;
#pragma unroll
            for (int rep = 0; rep < 5; ++rep) {
                const int n = lane + 64 * rep;
                if (n < 300) acc += LD<ISB>(sW2, d2 * 300 + n) * sW3row[n];
            }
            acc = waveReduceSum(acc);
            if (lane == 0) M33p[d3 * 102 + d2] = acc;
        }
        if (w == 0) {            // u[d3] = W3row . b2
            float acc = 0.f;
#pragma unroll
            for (int rep = 0; rep < 5; ++rep) {
                const int n = lane + 64 * rep;
                if (n < 300) acc += sW3row[n] * sb2v[n];
            }
            acc = waveReduceSum(acc);
            if (lane == 0) M33p[d3 * 102 + 100] = acc;
        } else if (w == 1) {     // v[d3] = W2[d3] . b3
            float acc = 0.f;
#pragma unroll
            for (int rep = 0; rep < 5; ++rep) {
                const int n = lane + 64 * rep;
                if (n < 300) acc += LD<ISB>(sW2, d3 * 300 + n) * sb3v[n];
            }
            acc = waveReduceSum(acc);
            if (lane == 0) M33p[d3 * 102 + 101] = acc;
        } else if (w == 2 && d3 == 0) {   // k0 = b2 . b3
            float acc = 0.f;
#pragma unroll
            for (int rep = 0; rep < 5; ++rep) {
                const int n = lane + 64 * rep;
                if (n < 300) acc += sb2v[n] * sb3v[n];
            }
            acc = waveReduceSum(acc);
            if (lane == 0) k0w[0] = acc;
        }
    } else {
        const int j = blk - 100;                 // 0..7, slice of 3750
        const float a0 = LD<ISB>(sA, 0);
        bool ok = true;
        for (int i = j * 3750 + tid; i < (j + 1) * 3750; i += 256)
            ok &= (LD<ISB>(sA, i) == a0);
        if (tid == 0) sb3v[300] = 1.f;
        __syncthreads();
        if (!ok) sb3v[300] = 0.f;                // benign same-value race
        __syncthreads();
        if (tid == 0) Afl[j] = sb3v[300];
        if (j == 0 && tid == 1) Afl[8] = a0;
    }
}

__global__ __launch_bounds__(256) void k_prep(
    const void* sW2, const void* sb2, const void* sW3, const void* sb3,
    const void* sA, float* M33p, float* k0w, float* Afl,
    const unsigned short* probe)
{
    __shared__ float sW3row[300], sb2v[300], sb3v[304];
    if (detect_bf16(probe)) prep_impl<true >(sW2, sb2, sW3, sb3, sA, M33p, k0w, Afl, sW3row, sb2v, sb3v);
    else                    prep_impl<false>(sW2, sb2, sW3, sb3, sA, M33p, k0w, Afl, sW3row, sb2v, sb3v);
}

// ---------------------------------------------------------------------------
// k_A: (R10, unchanged) GEMM1->LN->GEMM2->LN->t2g + delta/ddx + Mkv.
// ---------------------------------------------------------------------------
template<bool ISB>
__device__ __forceinline__ void a_impl(
    const void* __restrict__ text,
    const void* __restrict__ tW1, const void* __restrict__ tb1,
    const void* __restrict__ tg1, const void* __restrict__ tbe1,
    const void* __restrict__ tW2, const void* __restrict__ tb2,
    const void* __restrict__ tg2, const void* __restrict__ tbe2,
    const void* __restrict__ sW1, const void* __restrict__ sb1,
    const void* __restrict__ cW1, const void* __restrict__ cb1,
    const void* __restrict__ cW2, const void* __restrict__ cb2,
    float* __restrict__ ddx, float* __restrict__ t2g, float* __restrict__ Mkv,
    float (&xb)[4][DIN][2], float (&t1b)[4][H1][2], float (&t2b)[4][DM][2])
{
    const int w    = threadIdx.x >> 6;
    const int lane = threadIdx.x & 63;
    const int r0   = blockIdx.x * 8 + w * 2;

    if (lane < 50) {
#pragma unroll
        for (int r = 0; r < 2; ++r) {
            const float2 xv = LD2<ISB>(text, (r0 + r) * 50 + lane);
            xb[w][2 * lane][r]     = xv.x;
            xb[w][2 * lane + 1][r] = xv.y;
        }
    }

    const float2 b1v = LD2<ISB>(tb1, lane);
    float ax0 = b1v.x, ay0 = b1v.y, ax1 = b1v.x, ay1 = b1v.y;
    {
        float2 ring[10];
#pragma unroll
        for (int j = 0; j < 10; ++j) ring[j] = LD2<ISB>(tW1, j * 64 + lane);
        for (int kk = 0; kk < DIN; kk += 10) {
#pragma unroll
            for (int j = 0; j < 10; ++j) {
                const int k = kk + j;
                const float2 wv = ring[j];
                if (k + 10 < DIN) ring[j] = LD2<ISB>(tW1, (k + 10) * 64 + lane);
                const float2 xv = *(const float2*)&xb[w][k][0];
                ax0 += xv.x * wv.x; ay0 += xv.x * wv.y;
                ax1 += xv.y * wv.x; ay1 += xv.y * wv.y;
            }
        }
    }
    {
        float4 red = waveReduceSum4(make_float4(
            ax0 + ay0, ax0 * ax0 + ay0 * ay0,
            ax1 + ay1, ax1 * ax1 + ay1 * ay1));
        const float m0 = red.x * (1.f / 128.f);
        const float rs0 = rsqrtf(red.y * (1.f / 128.f) - m0 * m0 + 1e-5f);
        const float m1 = red.z * (1.f / 128.f);
        const float rs1 = rsqrtf(red.w * (1.f / 128.f) - m1 * m1 + 1e-5f);
        const float2 g = LD2<ISB>(tg1, lane), be = LD2<ISB>(tbe1, lane);
        float2 v;
        v.x = lrelu((ax0 - m0) * rs0 * g.x + be.x);
        v.y = lrelu((ax1 - m1) * rs1 * g.x + be.x);
        *(float2*)&t1b[w][2 * lane][0] = v;
        v.x = lrelu((ay0 - m0) * rs0 * g.y + be.y);
        v.y = lrelu((ay1 - m1) * rs1 * g.y + be.y);
        *(float2*)&t1b[w][2 * lane + 1][0] = v;
    }

    const bool act = lane < 50;
    const int  li  = act ? lane : 0;
    const float2 b2v = LD2<ISB>(tb2, li);
    float cx0 = b2v.x, cy0 = b2v.y, cx1 = b2v.x, cy1 = b2v.y;
    {
        float2 ring[8];
#pragma unroll
        for (int j = 0; j < 8; ++j) ring[j] = LD2<ISB>(tW2, j * 50 + li);
        for (int kk = 0; kk < H1; kk += 8) {
#pragma unroll
            for (int j = 0; j < 8; ++j) {
                const int k = kk + j;
                const float2 wv = ring[j];
                if (k + 8 < H1) ring[j] = LD2<ISB>(tW2, (k + 8) * 50 + li);
                const float2 tv = *(const float2*)&t1b[w][k][0];
                cx0 += tv.x * wv.x; cy0 += tv.x * wv.y;
                cx1 += tv.y * wv.x; cy1 += tv.y * wv.y;
            }
        }
    }
    float u0x, u0y, u1x, u1y;
    {
        float4 red = waveReduceSum4(act ? make_float4(
            cx0 + cy0, cx0 * cx0 + cy0 * cy0,
            cx1 + cy1, cx1 * cx1 + cy1 * cy1) : make_float4(0.f, 0.f, 0.f, 0.f));
        const float m0 = red.x * 0.01f;
        const float rs0 = rsqrtf(red.y * 0.01f - m0 * m0 + 1e-5f);
        const float m1 = red.z * 0.01f;
        const float rs1 = rsqrtf(red.w * 0.01f - m1 * m1 + 1e-5f);
        if (act) {
            const float2 g = LD2<ISB>(tg2, lane), be = LD2<ISB>(tbe2, lane);
            u0x = lrelu((cx0 - m0) * rs0 * g.x + be.x);
            u0y = lrelu((cy0 - m0) * rs0 * g.y + be.y);
            u1x = lrelu((cx1 - m1) * rs1 * g.x + be.x);
            u1y = lrelu((cy1 - m1) * rs1 * g.y + be.y);
            t2b[w][2 * lane][0] = u0x; t2b[w][2 * lane + 1][0] = u0y;
            t2b[w][2 * lane][1] = u1x; t2b[w][2 * lane + 1][1] = u1y;
            *(float2*)(t2g + (r0)     * DM + 2 * lane) = make_float2(u0x, u0y);
            *(float2*)(t2g + (r0 + 1) * DM + 2 * lane) = make_float2(u1x, u1y);
        }
    }

    const float2 sbv = LD2<ISB>(sb1, li);
    float dA0x = sbv.x, dA0y = sbv.y, dA1x = sbv.x, dA1y = sbv.y;
    {
        float2 ring[10];
#pragma unroll
        for (int j = 0; j < 10; ++j) ring[j] = LD2<ISB>(sW1, j * 50 + li);
        for (int kk = 0; kk < DM; kk += 10) {
#pragma unroll
            for (int j = 0; j < 10; ++j) {
                const int k = kk + j;
                const float2 wv = ring[j];
                if (k + 10 < DM) ring[j] = LD2<ISB>(sW1, (k + 10) * 50 + li);
                const float2 tv = *(const float2*)&t2b[w][k][0];
                dA0x += tv.x * wv.x; dA0y += tv.x * wv.y;
                dA1x += tv.y * wv.x; dA1y += tv.y * wv.y;
            }
        }
    }
    if (act) {
        float de0 = softplusf(dA0x), de1 = softplusf(dA0y);
        float4 o;
        o.x = de0; o.y = de0 * u0x; o.z = de1; o.w = de1 * u0y;
        *(float4*)(ddx + (r0) * (2 * DM) + 4 * lane) = o;
        de0 = softplusf(dA1x); de1 = softplusf(dA1y);
        o.x = de0; o.y = de0 * u1x; o.z = de1; o.w = de1 * u1y;
        *(float4*)(ddx + (r0 + 1) * (2 * DM) + 4 * lane) = o;
    }

    if (blockIdx.x == 0 && w == 0) {
#pragma unroll
        for (int t = lane; t < 200; t += 64) {
            const int d = t >> 1, j = t & 1;
            float m = 0.f;
            for (int i = 0; i < 50; ++i)
                m += LD<ISB>(cW1, d * 50 + i) * LD<ISB>(cW2, 2 * i + j);
            Mkv[t] = m;
        }
        if (lane < 2) {
            float kv = LD<ISB>(cb2, lane);
            for (int i = 0; i < 50; ++i)
                kv += LD<ISB>(cb1, i) * LD<ISB>(cW2, 2 * i + lane);
            Mkv[200 + lane] = kv;
        }
    }
}

__global__ __launch_bounds__(256, 1) void k_A(
    const void* text,
    const void* tW1, const void* tb1, const void* tg1, const void* tbe1,
    const void* tW2, const void* tb2, const void* tg2, const void* tbe2,
    const void* sW1, const void* sb1,
    const void* cW1, const void* cb1, const void* cW2, const void* cb2,
    float* ddx, float* t2g, float* Mkv, const unsigned short* probe)
{
    __shared__ __align__(16) float xb[4][DIN][2];
    __shared__ __align__(16) float t1b[4][H1][2];
    __shared__ __align__(16) float t2b[4][DM][2];
    if (detect_bf16(probe))
        a_impl<true >(text, tW1, tb1, tg1, tbe1, tW2, tb2, tg2, tbe2,
                      sW1, sb1, cW1, cb1, cW2, cb2, ddx, t2g, Mkv, xb, t1b, t2b);
    else
        a_impl<false>(text, tW1, tb1, tg1, tbe1, tW2, tb2, tg2, tbe2,
                      sW1, sb1, cW1, cb1, cW2, cb2, ddx, t2g, Mkv, xb, t1b, t2b);
}

// ---------------------------------------------------------------------------
// k_G v2 (fast path): grid 256 = (batch, t-chunk of 16). Block 4 waves.
// Phase 1: stage T2 (63x100, 102-padded) + sv (v column of M33p).
// Phase 2: per-wave rv slice (lanes 0..15); Z for 4 t-rows/wave via one
//          ring-prefetched M33p float2 stream (cols incl. ru=100, rv=101).
// Phase 3: G[t,s] = k0 + ru_t + rv_s + sum_k Z[t][k]*T2[s][k], wave-per-row,
//          lane-per-s, b64 LDS reads.
// ---------------------------------------------------------------------------
__global__ __launch_bounds__(256) void k_G(
    const float* __restrict__ t2g, const float* __restrict__ M33p,
    const float* __restrict__ k0w, float* __restrict__ G,
    const float* __restrict__ Afl)
{
    __shared__ __align__(16) float sT2[64 * 102];
    __shared__ __align__(16) float sZ[16][104];
    __shared__ float srv[64];
    __shared__ float sv[100];
    if (!flags_uniform(Afl)) return;
    const int b  = blockIdx.x >> 2;
    const int tc = blockIdx.x & 3;
    const int tid = threadIdx.x;
    const int w = tid >> 6, lane = tid & 63;

    for (int i = tid; i < 3150; i += 256) {
        const float2 v = *(const float2*)(t2g + b * 6300 + 2 * i);
        const int t = i / 50, k = 2 * (i % 50);
        sT2[t * 102 + k]     = v.x;
        sT2[t * 102 + k + 1] = v.y;
    }
    if (tid < 100) sv[tid] = M33p[tid * 102 + 101];
    __syncthreads();

    // rv[s] for all s (16 lanes per wave)
    if (lane < 16) {
        const int s = w * 16 + lane;
        if (s < SEQ) {
            float acc = 0.f;
#pragma unroll 4
            for (int k = 0; k < 100; ++k) acc += sT2[s * 102 + k] * sv[k];
            srv[s] = acc;
        }
    }

    // Z rows for this wave's 4 t's: one M33p stream feeds all 4
    {
        const int l2 = (lane < 51) ? 2 * lane : 0;
        int tg4[4];
#pragma unroll
        for (int r = 0; r < 4; ++r) {
            const int t = tc * 16 + w * 4 + r;
            tg4[r] = (t < SEQ) ? t : SEQ - 1;
        }
        float2 acc[4];
#pragma unroll
        for (int r = 0; r < 4; ++r) acc[r] = make_float2(0.f, 0.f);
        float2 ring[10];
#pragma unroll
        for (int j = 0; j < 10; ++j) ring[j] = *(const float2*)(M33p + j * 102 + l2);
        for (int kk = 0; kk < 100; kk += 10) {
#pragma unroll
            for (int j = 0; j < 10; ++j) {
                const int jj = kk + j;
                const float2 wv = ring[j];
                if (jj + 10 < 100) ring[j] = *(const float2*)(M33p + (jj + 10) * 102 + l2);
#pragma unroll
                for (int r = 0; r < 4; ++r) {
                    const float tv = sT2[tg4[r] * 102 + jj];
                    acc[r].x += tv * wv.x;
                    acc[r].y += tv * wv.y;
                }
            }
        }
        if (lane < 51) {
#pragma unroll
            for (int r = 0; r < 4; ++r)
                *(float2*)&sZ[w * 4 + r][l2] = acc[r];
        }
    }
    __syncthreads();

    // G rows
    const float kz = k0w[0];
    const int s = lane;
    const int sc = (s < SEQ) ? s : SEQ - 1;
#pragma unroll
    for (int r = 0; r < 4; ++r) {
        const int tl = w * 4 + r;
        const int t  = tc * 16 + tl;
        float acc = kz + sZ[tl][100] + srv[sc];
#pragma unroll 5
        for (int k2 = 0; k2 < 50; ++k2) {
            const float2 z  = *(const float2*)&sZ[tl][2 * k2];
            const float2 tv = *(const float2*)&sT2[sc * 102 + 2 * k2];
            acc += z.x * tv.x + z.y * tv.y;
        }
        if (t < SEQ && s < SEQ) G[b * 3969 + t * 63 + s] = acc;
    }
}

// ---------------------------------------------------------------------------
// k_Y v2 (fast path): grid 256 = (batch, 25-d chunk). Padded LDS layouts ->
// aligned float4 inner loop over s (both G row and V row contiguous).
// ---------------------------------------------------------------------------
__global__ __launch_bounds__(256) void k_Y(
    const float* __restrict__ ddx, const float* __restrict__ G,
    float* __restrict__ y, const float* __restrict__ Afl)
{
    __shared__ __align__(16) float sG[63][64];
    __shared__ __align__(16) float sDD[63][52];
    __shared__ __align__(16) float sV[25][68];
    __shared__ float sE[63][28];
    if (!flags_uniform(Afl)) return;
    const float a = Afl[8];
    const int b = blockIdx.x >> 2, c = blockIdx.x & 3;
    const int dbase = 25 * c;
    const int tid = threadIdx.x;

    for (int i = tid; i < 3969; i += 256) {
        const int t = i / 63, s = i - t * 63;
        sG[t][s] = G[b * 3969 + i];
    }
    for (int i = tid; i < 1575; i += 256) {
        const int t = i / 25, dd = i - t * 25;
        const float2 v = *(const float2*)(ddx + (b * SEQ + t) * 200 + 2 * (dbase + dd));
        sDD[t][2 * dd]     = v.x;
        sDD[t][2 * dd + 1] = v.y;
    }
    __syncthreads();
    if (tid < 25) {
        float D = 0.f;
        for (int t = 0; t < SEQ; ++t) {
            D += sDD[t][2 * tid];
            const float E = __expf(a * D);
            sE[t][tid] = E;
            sV[tid][t] = sDD[t][2 * tid + 1] / E;
        }
    }
    __syncthreads();
    for (int o = tid; o < 1575; o += 256) {
        const int t = o / 25, dd = o - t * 25;
        const int lim = t + 1, q = lim & ~3;
        float acc = 0.f;
        int s = 0;
        for (; s < q; s += 4) {
            const float4 g = *(const float4*)&sG[t][s];
            const float4 v = *(const float4*)&sV[dd][s];
            acc += g.x * v.x + g.y * v.y + g.z * v.z + g.w * v.w;
        }
        for (; s < lim; ++s) acc += sG[t][s] * sV[dd][s];
        y[(b * SEQ + t) * DM + dbase + dd] = sE[t][dd] * acc;
    }
}

// ---------------------------------------------------------------------------
// Fallback kernels (gated off when A uniform): R9 k_B + k_scan.
// ---------------------------------------------------------------------------
template<bool ISB>
__device__ __forceinline__ float4 LD4(const void* p, int i) {
    if (ISB) {
        const uint2 u = ((const uint2*)p)[i];
        float4 r;
        r.x = __uint_as_float(u.x << 16);
        r.y = __uint_as_float(u.x & 0xffff0000u);
        r.z = __uint_as_float(u.y << 16);
        r.w = __uint_as_float(u.y & 0xffff0000u);
        return r;
    } else return ((const float4*)p)[i];
}

template<bool ISB>
__device__ __forceinline__ void b_impl(
    const float* __restrict__ t2g,
    const void* __restrict__ sW2, const void* __restrict__ sb2,
    const void* __restrict__ sW3, const void* __restrict__ sb3,
    float* __restrict__ BC, float (&sT)[DM][8])
{
    const int t  = threadIdx.x;
    const int r0 = blockIdx.x * 8;
    if (t < DM) {
#pragma unroll
        for (int r = 0; r < 8; ++r) sT[t][r] = t2g[(r0 + r) * DM + t];
    }
    __syncthreads();
    const bool isB = t < 75;
    const bool valid = t < 150;
    const int colbase = isB ? 4 * t : (valid ? 4 * (t - 75) : 0);
    const void* Wp   = isB ? sW2 : sW3;
    const void* bias = isB ? sb2 : sb3;
    const int rs4 = NS >> 2;
    const int cb4 = colbase >> 2;
    float4 acc[8];
    {
        const float4 bv = LD4<ISB>(bias, cb4);
#pragma unroll
        for (int r = 0; r < 8; ++r) acc[r] = bv;
    }
    float4 ring[4];
#pragma unroll
    for (int j = 0; j < 4; ++j) ring[j] = LD4<ISB>(Wp, j * rs4 + cb4);
    for (int kk = 0; kk < DM; kk += 4) {
#pragma unroll
        for (int j = 0; j < 4; ++j) {
            const int k = kk + j;
            const float4 wv = ring[j];
            if (k + 4 < DM) ring[j] = LD4<ISB>(Wp, (k + 4) * rs4 + cb4);
            const float4 lo = *(const float4*)&sT[k][0];
            const float4 hi = *(const float4*)&sT[k][4];
            acc[0].x += lo.x * wv.x; acc[0].y += lo.x * wv.y; acc[0].z += lo.x * wv.z; acc[0].w += lo.x * wv.w;
            acc[1].x += lo.y * wv.x; acc[1].y += lo.y * wv.y; acc[1].z += lo.y * wv.z; acc[1].w += lo.y * wv.w;
            acc[2].x += lo.z * wv.x; acc[2].y += lo.z * wv.y; acc[2].z += lo.z * wv.z; acc[2].w += lo.z * wv.w;
            acc[3].x += lo.w * wv.x; acc[3].y += lo.w * wv.y; acc[3].z += lo.w * wv.z; acc[3].w += lo.w * wv.w;
            acc[4].x += hi.x * wv.x; acc[4].y += hi.x * wv.y; acc[4].z += hi.x * wv.z; acc[4].w += hi.x * wv.w;
            acc[5].x += hi.y * wv.x; acc[5].y += hi.y * wv.y; acc[5].z += hi.y * wv.z; acc[5].w += hi.y * wv.w;
            acc[6].x += hi.z * wv.x; acc[6].y += hi.z * wv.y; acc[6].z += hi.z * wv.z; acc[6].w += hi.z * wv.w;
            acc[7].x += hi.w * wv.x; acc[7].y += hi.w * wv.y; acc[7].z += hi.w * wv.z; acc[7].w += hi.w * wv.w;
        }
    }
    if (valid) {
        const int off = isB ? 0 : 1;
#pragma unroll
        for (int r = 0; r < 8; ++r) {
            float* bp = BC + (r0 + r) * (2 * NS) + 2 * colbase + off;
            bp[0] = acc[r].x; bp[2] = acc[r].y;
            bp[4] = acc[r].z; bp[6] = acc[r].w;
        }
    }
}

__global__ __launch_bounds__(192, 1) void k_B(
    const float* t2g, const void* sW2, const void* sb2,
    const void* sW3, const void* sb3, float* BC,
    const float* Afl, const unsigned short* probe)
{
    __shared__ __align__(16) float sT[DM][8];
    if (flags_uniform(Afl)) return;
    if (detect_bf16(probe)) b_impl<true >(t2g, sW2, sb2, sW3, sb3, BC, sT);
    else                    b_impl<false>(t2g, sW2, sb2, sW3, sb3, BC, sT);
}

template<bool ISB>
__device__ __forceinline__ void scan_impl(
    const float* __restrict__ ddx, const float* __restrict__ BC,
    const void* __restrict__ sA, float* __restrict__ y,
    float (&sacc)[4][16][2][68])
{
    const int w    = threadIdx.x >> 6;
    const int lane = threadIdx.x & 63;
    const int wid  = blockIdx.x * 4 + w;
    const int b    = wid / 50;
    const int dp   = wid % 50;
    const int d0   = 2 * dp, d1 = d0 + 1;

    int nc[5]; bool nv[5];
    float A0[5], A1[5], h0[5], h1[5];
#pragma unroll
    for (int c = 0; c < 5; ++c) {
        const int n = lane + 64 * c;
        nv[c] = n < NS;
        nc[c] = nv[c] ? n : 0;
        A0[c] = nv[c] ? LD<ISB>(sA, d0 * NS + nc[c]) : 0.f;
        A1[c] = nv[c] ? LD<ISB>(sA, d1 * NS + nc[c]) : 0.f;
        h0[c] = 0.f; h1[c] = 0.f;
    }
    const float* ddp = ddx + (b * SEQ) * (2 * DM) + 4 * dp;
    const float* BCp = BC  + (b * SEQ) * (2 * NS);
    float*       yp  = y   + (b * SEQ) * DM + d0;

    float4 pdd[3];
    float2 pbc[3][5];
#pragma unroll
    for (int j = 0; j < 3; ++j) {
        pdd[j] = *(const float4*)(ddp + j * (2 * DM));
#pragma unroll
        for (int c = 0; c < 5; ++c)
            pbc[j][c] = nv[c] ? *(const float2*)(BCp + j * (2 * NS) + 2 * nc[c])
                              : make_float2(0.f, 0.f);
    }
    const int pr = lane >> 1;
    const int hh = lane & 1;
    const int sa = pr & 15;
    const int aa = pr >> 4;

#pragma unroll 3
    for (int l = 0; l < SEQ; ++l) {
        const int bi = l % 3;
        const float4 dd = pdd[bi];
        float2 bc[5];
#pragma unroll
        for (int c = 0; c < 5; ++c) bc[c] = pbc[bi][c];
        if (l + 3 < SEQ) {
            pdd[bi] = *(const float4*)(ddp + (l + 3) * (2 * DM));
#pragma unroll
            for (int c = 0; c < 5; ++c)
                pbc[bi][c] = nv[c] ? *(const float2*)(BCp + (l + 3) * (2 * NS) + 2 * nc[c])
                                   : make_float2(0.f, 0.f);
        }
        float a0 = 0.f, a1 = 0.f;
#pragma unroll
        for (int c = 0; c < 5; ++c) {
            h0[c] = __expf(dd.x * A0[c]) * h0[c] + dd.y * bc[c].x;
            a0 += bc[c].y * h0[c];
            h1[c] = __expf(dd.z * A1[c]) * h1[c] + dd.w * bc[c].x;
            a1 += bc[c].y * h1[c];
        }
        const int s = l & 15;
        sacc[w][s][0][lane] = a0;
        sacc[w][s][1][lane] = a1;

        if (s == 15 || l == SEQ - 1) {
            const int l0 = l & ~15;
            const int cs = l - l0 + 1;
            float sum = 0.f;
            if (sa < cs) {
                const float* rowp = &sacc[w][sa][aa][hh * 32];
#pragma unroll
                for (int i = 0; i < 8; ++i) {
                    const float4 v = *(const float4*)(rowp + 4 * i);
                    sum += v.x + v.y + v.z + v.w;
                }
            }
            sum += __shfl_xor(sum, 1, 64);
            if (hh == 0 && sa < cs) yp[(l0 + sa) * DM + aa] = sum;
        }
    }
}

__global__ __launch_bounds__(256) void k_scan(
    const float* ddx, const float* BC, const void* sA, float* y,
    const float* Afl, const unsigned short* probe)
{
    __shared__ __align__(16) float sacc[4][16][2][68];
    if (flags_uniform(Afl)) return;
    if (detect_bf16(probe)) scan_impl<true >(ddx, BC, sA, y, sacc);
    else                    scan_impl<false>(ddx, BC, sA, y, sacc);
}

// ---------------------------------------------------------------------------
// k_head: out[row] = y[row] @ M + k. Thread per row.
// ---------------------------------------------------------------------------
template<bool ISB>
__device__ __forceinline__ void head_impl(
    const float* __restrict__ y, const float* __restrict__ Mkv,
    void* __restrict__ outp)
{
    const int row = blockIdx.x * 256 + threadIdx.x;
    if (row >= ROWS) return;
    float a0 = Mkv[200], a1 = Mkv[201];
    const float* yr = y + row * DM;
#pragma unroll 4
    for (int k = 0; k < DM; ++k) {
        const float v = yr[k];
        const float2 m = *(const float2*)(Mkv + 2 * k);
        a0 += v * m.x;
        a1 += v * m.y;
    }
    if (ISB) {
        ((bf16*)outp)[row * 2 + 0] = __float2bfloat16(a0);
        ((bf16*)outp)[row * 2 + 1] = __float2bfloat16(a1);
    } else {
        *(float2*)((float*)outp + row * 2) = make_float2(a0, a1);
    }
}

__global__ __launch_bounds__(256) void k_head(
    const float* y, const float* Mkv, void* outp, const unsigned short* probe)
{
    if (detect_bf16(probe)) head_impl<true >(y, Mkv, outp);
    else                    head_impl<false>(y, Mkv, outp);
}

// ---------------------------------------------------------------------------
extern "C" void kernel_launch(void* const* d_in, const int* in_sizes, int n_in,
                              void* d_out, int out_size, void* d_ws, size_t ws_size,
                              hipStream_t stream)
{
    const void* text = d_in[0];
    const void* tW1  = d_in[3];
    const void* tb1  = d_in[4];
    const void* tg1  = d_in[5];
    const void* tbe1 = d_in[6];
    const void* tW2  = d_in[7];
    const void* tb2  = d_in[8];
    const void* tg2  = d_in[9];
    const void* tbe2 = d_in[10];
    const void* sW1  = d_in[11];
    const void* sb1  = d_in[12];
    const void* sW2  = d_in[13];
    const void* sb2  = d_in[14];
    const void* sW3  = d_in[15];
    const void* sb3  = d_in[16];
    const void* sA   = d_in[17];
    const void* cW1  = d_in[34];
    const void* cb1  = d_in[35];
    const void* cW2  = d_in[36];
    const void* cb2  = d_in[37];
    const unsigned short* probe = (const unsigned short*)d_in[3];

    float* ws   = (float*)d_ws;
    float* ddx  = ws;                         // ROWS*200
    float* BCv  = ddx + ROWS * 2 * DM;        // ROWS*600 (fallback BC)
    float* Gv   = BCv;                        // alias: 64*3969 fast-path G
    float* yv   = BCv + ROWS * 2 * NS;        // ROWS*100 (t2g, then y)
    float* Mkv  = yv + ROWS * DM;             // 202
    float* M33p = Mkv + 202;                  // 100*102 = 10200
    float* k0w  = M33p + 10200;               // 1
    float* Afl  = k0w + 1;                    // 9 (8 flags + a)
    float* t2g  = yv;                         // alias: t2 consumed before y write

    k_prep<<<108, 256, 0, stream>>>(sW2, sb2, sW3, sb3, sA,
                                    M33p, k0w, Afl, probe);

    k_A<<<ROWS / 8, 256, 0, stream>>>(
        text, tW1, tb1, tg1, tbe1, tW2, tb2, tg2, tbe2,
        sW1, sb1, cW1, cb1, cW2, cb2, ddx, t2g, Mkv, probe);

    k_B<<<ROWS / 8, 192, 0, stream>>>(t2g, sW2, sb2, sW3, sb3, BCv, Afl, probe);

    k_G<<<BATCH * 4, 256, 0, stream>>>(t2g, M33p, k0w, Gv, Afl);

    k_Y<<<BATCH * 4, 256, 0, stream>>>(ddx, Gv, yv, Afl);

    k_scan<<<3200 / 4, 256, 0, stream>>>(ddx, BCv, sA, yv, Afl, probe);

    k_head<<<(ROWS + 255) / 256, 256, 0, stream>>>(yv, Mkv, d_out, probe);
}

// Round 12
// 192.737 us; speedup vs baseline: 1.5099x; 1.1605x over previous
//
#include <hip/hip_runtime.h>
#include <hip/hip_bf16.h>

// Simple_6270652252303. Inputs float32 (detector-verified; bf16 path kept).
// sA constant (runtime-verified) => closed-form S6:
//   y[b,t,d] = E_t[d] * sum_{s<=t} G_b[t,s] * dx_s[d]/E_s[d]
//   G_b[t,s] = Z_t.T2_s + ru_t + rv_s + k0,  Z = T2@M33p (cols 100=u,101=v)
// R12: k_A stages weights in LDS (shared by all waves; kills the L2-latency
// ring stalls that made k_A 40us); prep+Mkv folded into k_A's grid; k_G/k_Y
// at 512 blocks; y written TRANSPOSED (k_head coalesced). Fallback gated.

typedef __hip_bfloat16 bf16;

#define BATCH 64
#define SEQ   63
#define ROWS  (BATCH * SEQ)   // 4032
#define DIN   100
#define H1    128
#define DM    100
#define NS    300

__device__ __forceinline__ float2 up2(unsigned u) {
    float2 r;
    r.x = __uint_as_float(u << 16);
    r.y = __uint_as_float(u & 0xffff0000u);
    return r;
}
template<bool ISB>
__device__ __forceinline__ float LD(const void* p, int i) {
    if (ISB) return __bfloat162float(((const bf16*)p)[i]);
    else     return ((const float*)p)[i];
}
template<bool ISB>
__device__ __forceinline__ float2 LD2(const void* p, int i) {   // elems 2i,2i+1
    if (ISB) return up2(((const unsigned*)p)[i]);
    else     return ((const float2*)p)[i];
}
__device__ __forceinline__ float waveReduceSum(float v) {
#pragma unroll
    for (int off = 32; off > 0; off >>= 1) v += __shfl_xor(v, off, 64);
    return v;
}
__device__ __forceinline__ float4 waveReduceSum4(float4 v) {
#pragma unroll
    for (int off = 32; off > 0; off >>= 1) {
        const float a = __shfl_xor(v.x, off, 64);
        const float b = __shfl_xor(v.y, off, 64);
        const float c = __shfl_xor(v.z, off, 64);
        const float d = __shfl_xor(v.w, off, 64);
        v.x += a; v.y += b; v.z += c; v.w += d;
    }
    return v;
}
__device__ __forceinline__ float lrelu(float x) { return x >= 0.f ? x : 0.01f * x; }
__device__ __forceinline__ float softplusf(float x) {
    return (x > 20.f) ? x : log1pf(__expf(x));
}
__device__ __forceinline__ bool flags_uniform(const float* __restrict__ f) {
    bool u = true;
#pragma unroll
    for (int i = 0; i < 8; ++i) u &= (f[i] > 0.5f);
    return u;
}
__device__ __forceinline__ bool detect_bf16(const unsigned short* __restrict__ probe) {
    const int l = threadIdx.x & 63;
    const unsigned u0 = probe[l * 2];
    const unsigned u1 = probe[l * 2 + 1];
    const float v0 = fabsf(__uint_as_float(u0 << 16));
    const float v1 = fabsf(__uint_as_float(u1 << 16));
    const bool big = !(v0 < 1000.f) || !(v1 < 1000.f);
    const bool zero_even = (u0 == 0u);
    const unsigned long long mb = __ballot(big);
    const unsigned long long mz = __ballot(zero_even);
    return (mb == 0ULL) && (__popcll(mz) < 32);
}

// ---------------------------------------------------------------------------
// k_A: grid 613. Blocks 0..503: main row pipeline (8 rows/block, 2 rows/wave).
//   Weights staged in LDS per phase (tW1 -> tW2 -> sW1), block barriers
//   between phases; inner loops are pure VALU + ds_read (no global latency).
// Blocks 504..603: M33p row (d3 = blk-504) + u/v cols (+k0 on 504).
// Blocks 604..611: A-uniformity check. Block 612: collapsed head Mkv.
// ---------------------------------------------------------------------------
template<bool ISB>
__device__ __forceinline__ void a_main(
    const void* __restrict__ text,
    const void* __restrict__ tW1, const void* __restrict__ tb1,
    const void* __restrict__ tg1, const void* __restrict__ tbe1,
    const void* __restrict__ tW2, const void* __restrict__ tb2,
    const void* __restrict__ tg2, const void* __restrict__ tbe2,
    const void* __restrict__ sW1w, const void* __restrict__ sb1,
    float* __restrict__ ddx, float* __restrict__ t2g,
    float* __restrict__ sW,
    float (&xb)[4][DIN][2], float (&t1b)[4][H1][2], float (&t2b)[4][DM][2])
{
    const int tid  = threadIdx.x;
    const int w    = tid >> 6;
    const int lane = tid & 63;
    const int r0   = blockIdx.x * 8 + w * 2;

    if (lane < 50) {
#pragma unroll
        for (int r = 0; r < 2; ++r) {
            const float2 xv = LD2<ISB>(text, (r0 + r) * 50 + lane);
            xb[w][2 * lane][r]     = xv.x;
            xb[w][2 * lane + 1][r] = xv.y;
        }
    }
    // ---- stage tW1 (100x128 = 6400 float2) ----
    for (int i = tid; i < 6400; i += 256)
        *(float2*)&sW[2 * i] = LD2<ISB>(tW1, i);
    __syncthreads();

    // ---- GEMM1 (100 -> 128) from LDS ----
    const float2 b1v = LD2<ISB>(tb1, lane);
    float ax0 = b1v.x, ay0 = b1v.y, ax1 = b1v.x, ay1 = b1v.y;
#pragma unroll 10
    for (int k = 0; k < DIN; ++k) {
        const float2 wv = *(const float2*)&sW[k * 128 + 2 * lane];
        const float2 xv = *(const float2*)&xb[w][k][0];
        ax0 += xv.x * wv.x; ay0 += xv.x * wv.y;
        ax1 += xv.y * wv.x; ay1 += xv.y * wv.y;
    }
    {   // LN(128)+LReLU
        float4 red = waveReduceSum4(make_float4(
            ax0 + ay0, ax0 * ax0 + ay0 * ay0,
            ax1 + ay1, ax1 * ax1 + ay1 * ay1));
        const float m0 = red.x * (1.f / 128.f);
        const float rs0 = rsqrtf(red.y * (1.f / 128.f) - m0 * m0 + 1e-5f);
        const float m1 = red.z * (1.f / 128.f);
        const float rs1 = rsqrtf(red.w * (1.f / 128.f) - m1 * m1 + 1e-5f);
        const float2 g = LD2<ISB>(tg1, lane), be = LD2<ISB>(tbe1, lane);
        float2 v;
        v.x = lrelu((ax0 - m0) * rs0 * g.x + be.x);
        v.y = lrelu((ax1 - m1) * rs1 * g.x + be.x);
        *(float2*)&t1b[w][2 * lane][0] = v;
        v.x = lrelu((ay0 - m0) * rs0 * g.y + be.y);
        v.y = lrelu((ay1 - m1) * rs1 * g.y + be.y);
        *(float2*)&t1b[w][2 * lane + 1][0] = v;
    }
    __syncthreads();                 // all waves done with tW1

    // ---- stage tW2 (128x100 = 6400 float2) ----
    for (int i = tid; i < 6400; i += 256)
        *(float2*)&sW[2 * i] = LD2<ISB>(tW2, i);
    __syncthreads();

    // ---- GEMM2 (128 -> 100) from LDS ----
    const bool act = lane < 50;
    const int  li  = act ? lane : 0;
    const float2 b2v = LD2<ISB>(tb2, li);
    float cx0 = b2v.x, cy0 = b2v.y, cx1 = b2v.x, cy1 = b2v.y;
#pragma unroll 8
    for (int k = 0; k < H1; ++k) {
        const float2 wv = *(const float2*)&sW[k * 100 + 2 * li];
        const float2 tv = *(const float2*)&t1b[w][k][0];
        cx0 += tv.x * wv.x; cy0 += tv.x * wv.y;
        cx1 += tv.y * wv.x; cy1 += tv.y * wv.y;
    }
    float u0x, u0y, u1x, u1y;
    {   // LN(100)+LReLU -> t2b, t2g
        float4 red = waveReduceSum4(act ? make_float4(
            cx0 + cy0, cx0 * cx0 + cy0 * cy0,
            cx1 + cy1, cx1 * cx1 + cy1 * cy1) : make_float4(0.f, 0.f, 0.f, 0.f));
        const float m0 = red.x * 0.01f;
        const float rs0 = rsqrtf(red.y * 0.01f - m0 * m0 + 1e-5f);
        const float m1 = red.z * 0.01f;
        const float rs1 = rsqrtf(red.w * 0.01f - m1 * m1 + 1e-5f);
        if (act) {
            const float2 g = LD2<ISB>(tg2, lane), be = LD2<ISB>(tbe2, lane);
            u0x = lrelu((cx0 - m0) * rs0 * g.x + be.x);
            u0y = lrelu((cy0 - m0) * rs0 * g.y + be.y);
            u1x = lrelu((cx1 - m1) * rs1 * g.x + be.x);
            u1y = lrelu((cy1 - m1) * rs1 * g.y + be.y);
            t2b[w][2 * lane][0] = u0x; t2b[w][2 * lane + 1][0] = u0y;
            t2b[w][2 * lane][1] = u1x; t2b[w][2 * lane + 1][1] = u1y;
            *(float2*)(t2g + (r0)     * DM + 2 * lane) = make_float2(u0x, u0y);
            *(float2*)(t2g + (r0 + 1) * DM + 2 * lane) = make_float2(u1x, u1y);
        }
    }
    __syncthreads();                 // all waves done with tW2

    // ---- stage sW1 (100x100 = 5000 float2) ----
    for (int i = tid; i < 5000; i += 256)
        *(float2*)&sW[2 * i] = LD2<ISB>(sW1w, i);
    __syncthreads();

    // ---- delta (100 cols) from LDS -> ddx {de, de*t2} ----
    const float2 sbv = LD2<ISB>(sb1, li);
    float dA0x = sbv.x, dA0y = sbv.y, dA1x = sbv.x, dA1y = sbv.y;
#pragma unroll 10
    for (int k = 0; k < DM; ++k) {
        const float2 wv = *(const float2*)&sW[k * 100 + 2 * li];
        const float2 tv = *(const float2*)&t2b[w][k][0];
        dA0x += tv.x * wv.x; dA0y += tv.x * wv.y;
        dA1x += tv.y * wv.x; dA1y += tv.y * wv.y;
    }
    if (act) {
        float de0 = softplusf(dA0x), de1 = softplusf(dA0y);
        float4 o;
        o.x = de0; o.y = de0 * u0x; o.z = de1; o.w = de1 * u0y;
        *(float4*)(ddx + (r0) * (2 * DM) + 4 * lane) = o;
        de0 = softplusf(dA1x); de1 = softplusf(dA1y);
        o.x = de0; o.y = de0 * u1x; o.z = de1; o.w = de1 * u1y;
        *(float4*)(ddx + (r0 + 1) * (2 * DM) + 4 * lane) = o;
    }
}

// prep duty: M33p row d3 (+ u,v cols; k0 on d3==0). Uses sW[0..943] as scratch.
template<bool ISB>
__device__ __forceinline__ void a_prep(
    const void* __restrict__ sW2, const void* __restrict__ sb2,
    const void* __restrict__ sW3, const void* __restrict__ sb3,
    float* __restrict__ M33p, float* __restrict__ k0w, float* __restrict__ sW,
    int d3)
{
    const int tid = threadIdx.x;
    const int w = tid >> 6, lane = tid & 63;
    float* W3row = sW;          // 300
    float* b2v   = sW + 320;    // 300
    float* b3v   = sW + 640;    // 300
    for (int i = tid; i < 300; i += 256) {
        W3row[i] = LD<ISB>(sW3, d3 * 300 + i);
        b2v[i]   = LD<ISB>(sb2, i);
        b3v[i]   = LD<ISB>(sb3, i);
    }
    __syncthreads();
    // wave w: d2 rows {w*25 .. w*25+24}, groups of 4 (6 groups + 1 leftover)
    for (int g = 0; g < 6; ++g) {
        const int d2 = w * 25 + g * 4;
        float4 p = make_float4(0.f, 0.f, 0.f, 0.f);
#pragma unroll
        for (int rep = 0; rep < 5; ++rep) {
            const int n = lane + 64 * rep;
            if (n < 300) {
                const float w3 = W3row[n];
                p.x += LD<ISB>(sW2, (d2 + 0) * 300 + n) * w3;
                p.y += LD<ISB>(sW2, (d2 + 1) * 300 + n) * w3;
                p.z += LD<ISB>(sW2, (d2 + 2) * 300 + n) * w3;
                p.w += LD<ISB>(sW2, (d2 + 3) * 300 + n) * w3;
            }
        }
        p = waveReduceSum4(p);
        if (lane == 0) {
            M33p[d3 * 102 + d2 + 0] = p.x;
            M33p[d3 * 102 + d2 + 1] = p.y;
            M33p[d3 * 102 + d2 + 2] = p.z;
            M33p[d3 * 102 + d2 + 3] = p.w;
        }
    }
    {   // leftover row d2 = w*25+24, plus u (w0), v (w1), k0 (w2, d3==0)
        const int d2 = w * 25 + 24;
        float4 p = make_float4(0.f, 0.f, 0.f, 0.f);
#pragma unroll
        for (int rep = 0; rep < 5; ++rep) {
            const int n = lane + 64 * rep;
            if (n < 300) {
                p.x += LD<ISB>(sW2, d2 * 300 + n) * W3row[n];
                if (w == 0) p.y += W3row[n] * b2v[n];                       // u[d3]
                if (w == 1) p.y += LD<ISB>(sW2, d3 * 300 + n) * b3v[n];     // v[d3]
                if (w == 2 && d3 == 0) p.y += b2v[n] * b3v[n];              // k0
            }
        }
        p = waveReduceSum4(p);
        if (lane == 0) {
            M33p[d3 * 102 + d2] = p.x;
            if (w == 0) M33p[d3 * 102 + 100] = p.y;
            if (w == 1) M33p[d3 * 102 + 101] = p.y;
            if (w == 2 && d3 == 0) k0w[0] = p.y;
        }
    }
}

template<bool ISB>
__device__ __forceinline__ void a_check(
    const void* __restrict__ sA, float* __restrict__ Afl,
    float* __restrict__ sW, int j)
{
    const int tid = threadIdx.x;
    const float a0 = LD<ISB>(sA, 0);
    bool ok = true;
    for (int i = j * 3750 + tid; i < (j + 1) * 3750; i += 256)
        ok &= (LD<ISB>(sA, i) == a0);
    if (tid == 0) sW[960] = 1.f;
    __syncthreads();
    if (!ok) sW[960] = 0.f;          // benign same-value race
    __syncthreads();
    if (tid == 0) Afl[j] = sW[960];
    if (j == 0 && tid == 1) Afl[8] = a0;
}

template<bool ISB>
__device__ __forceinline__ void a_mkv(
    const void* __restrict__ cW1, const void* __restrict__ cb1,
    const void* __restrict__ cW2, const void* __restrict__ cb2,
    float* __restrict__ Mkv)
{
    const int t = threadIdx.x;
    if (t < 200) {
        const int d = t >> 1, j = t & 1;
        float m = 0.f;
#pragma unroll 5
        for (int i = 0; i < 50; ++i)
            m += LD<ISB>(cW1, d * 50 + i) * LD<ISB>(cW2, 2 * i + j);
        Mkv[t] = m;
    } else if (t < 202) {
        const int j = t - 200;
        float kv = LD<ISB>(cb2, j);
#pragma unroll 5
        for (int i = 0; i < 50; ++i)
            kv += LD<ISB>(cb1, i) * LD<ISB>(cW2, 2 * i + j);
        Mkv[200 + j] = kv;
    }
}

__global__ __launch_bounds__(256) void k_A(
    const void* text,
    const void* tW1, const void* tb1, const void* tg1, const void* tbe1,
    const void* tW2, const void* tb2, const void* tg2, const void* tbe2,
    const void* sW1w, const void* sb1,
    const void* sW2, const void* sb2, const void* sW3, const void* sb3,
    const void* sA,
    const void* cW1, const void* cb1, const void* cW2, const void* cb2,
    float* ddx, float* t2g, float* Mkv, float* M33p, float* k0w, float* Afl,
    const unsigned short* probe)
{
    __shared__ __align__(16) float sW[12800];       // 51.2 KB (phase weights)
    __shared__ __align__(16) float xb[4][DIN][2];
    __shared__ __align__(16) float t1b[4][H1][2];
    __shared__ __align__(16) float t2b[4][DM][2];
    const bool isb = detect_bf16(probe);
    const int blk = blockIdx.x;
    if (blk < 504) {
        if (isb) a_main<true >(text, tW1, tb1, tg1, tbe1, tW2, tb2, tg2, tbe2,
                               sW1w, sb1, ddx, t2g, sW, xb, t1b, t2b);
        else     a_main<false>(text, tW1, tb1, tg1, tbe1, tW2, tb2, tg2, tbe2,
                               sW1w, sb1, ddx, t2g, sW, xb, t1b, t2b);
    } else if (blk < 604) {
        if (isb) a_prep<true >(sW2, sb2, sW3, sb3, M33p, k0w, sW, blk - 504);
        else     a_prep<false>(sW2, sb2, sW3, sb3, M33p, k0w, sW, blk - 504);
    } else if (blk < 612) {
        if (isb) a_check<true >(sA, Afl, sW, blk - 604);
        else     a_check<false>(sA, Afl, sW, blk - 604);
    } else {
        if (isb) a_mkv<true >(cW1, cb1, cW2, cb2, Mkv);
        else     a_mkv<false>(cW1, cb1, cW2, cb2, Mkv);
    }
}

// ---------------------------------------------------------------------------
// k_G (fast path): grid 512 = (batch, t-chunk of 8). 2 t-rows per wave.
// G[t,s] = k0 + Z[t][100] + rv_s + sum_k Z[t][k]*T2[s][k].
// ---------------------------------------------------------------------------
__global__ __launch_bounds__(256) void k_G(
    const float* __restrict__ t2g, const float* __restrict__ M33p,
    const float* __restrict__ k0w, float* __restrict__ G,
    const float* __restrict__ Afl)
{
    __shared__ __align__(16) float sT2[64 * 102];
    __shared__ __align__(16) float sZ[8][104];
    __shared__ float srv[64];
    __shared__ float sv[100];
    if (!flags_uniform(Afl)) return;
    const int b  = blockIdx.x >> 3;
    const int tc = blockIdx.x & 7;
    const int tid = threadIdx.x;
    const int w = tid >> 6, lane = tid & 63;

    for (int i = tid; i < 3150; i += 256) {
        const float2 v = *(const float2*)(t2g + b * 6300 + 2 * i);
        const int t = i / 50, k = 2 * (i % 50);
        sT2[t * 102 + k]     = v.x;
        sT2[t * 102 + k + 1] = v.y;
    }
    if (tid < 100) sv[tid] = M33p[tid * 102 + 101];
    __syncthreads();

    if (lane < 16) {                 // rv[s], 16 s per wave
        const int s = w * 16 + lane;
        if (s < SEQ) {
            float acc = 0.f;
#pragma unroll 4
            for (int k = 0; k < 100; ++k) acc += sT2[s * 102 + k] * sv[k];
            srv[s] = acc;
        }
    }

    {   // Z rows (2 per wave) via one ring-prefetched M33p stream
        const int l2 = (lane < 51) ? 2 * lane : 0;
        int tg2i[2];
#pragma unroll
        for (int r = 0; r < 2; ++r) {
            const int t = tc * 8 + w * 2 + r;
            tg2i[r] = (t < SEQ) ? t : SEQ - 1;
        }
        float2 acc[2];
        acc[0] = make_float2(0.f, 0.f);
        acc[1] = make_float2(0.f, 0.f);
        float2 ring[10];
#pragma unroll
        for (int j = 0; j < 10; ++j) ring[j] = *(const float2*)(M33p + j * 102 + l2);
        for (int kk = 0; kk < 100; kk += 10) {
#pragma unroll
            for (int j = 0; j < 10; ++j) {
                const int jj = kk + j;
                const float2 wv = ring[j];
                if (jj + 10 < 100) ring[j] = *(const float2*)(M33p + (jj + 10) * 102 + l2);
#pragma unroll
                for (int r = 0; r < 2; ++r) {
                    const float tv = sT2[tg2i[r] * 102 + jj];
                    acc[r].x += tv * wv.x;
                    acc[r].y += tv * wv.y;
                }
            }
        }
        if (lane < 51) {
#pragma unroll
            for (int r = 0; r < 2; ++r)
                *(float2*)&sZ[w * 2 + r][l2] = acc[r];
        }
    }
    __syncthreads();

    const float kz = k0w[0];
    const int s = lane;
    const int sc = (s < SEQ) ? s : SEQ - 1;
#pragma unroll
    for (int r = 0; r < 2; ++r) {
        const int tl = w * 2 + r;
        const int t  = tc * 8 + tl;
        float acc = kz + sZ[tl][100] + srv[sc];
#pragma unroll 5
        for (int k2 = 0; k2 < 50; ++k2) {
            const float2 z  = *(const float2*)&sZ[tl][2 * k2];
            const float2 tv = *(const float2*)&sT2[sc * 102 + 2 * k2];
            acc += z.x * tv.x + z.y * tv.y;
        }
        if (t < SEQ && s < SEQ) G[b * 3969 + t * 63 + s] = acc;
    }
}

// ---------------------------------------------------------------------------
// k_Y (fast path): grid 512 = (batch, 13-d chunk). Writes y TRANSPOSED:
// yT[d * ROWS + b*SEQ + t]  (k_head reads it coalesced).
// ---------------------------------------------------------------------------
__global__ __launch_bounds__(256) void k_Y(
    const float* __restrict__ ddx, const float* __restrict__ G,
    float* __restrict__ yT, const float* __restrict__ Afl)
{
    __shared__ __align__(16) float sG[63][64];
    __shared__ __align__(16) float sDD[63][28];
    __shared__ __align__(16) float sV[13][68];
    __shared__ float sE[63][16];
    if (!flags_uniform(Afl)) return;
    const float a = Afl[8];
    const int b = blockIdx.x >> 3, c = blockIdx.x & 7;
    const int dbase = 13 * c;                       // 0..91; last chunk 9 wide
    const int tid = threadIdx.x;

    for (int i = tid; i < 3969; i += 256) {
        const int t = i / 63, s = i - t * 63;
        sG[t][s] = G[b * 3969 + i];
    }
    for (int i = tid; i < 819; i += 256) {          // 63*13
        const int t = i / 13, dd = i - t * 13;
        if (dbase + dd < DM) {
            const float2 v = *(const float2*)(ddx + (b * SEQ + t) * 200 + 2 * (dbase + dd));
            sDD[t][2 * dd]     = v.x;
            sDD[t][2 * dd + 1] = v.y;
        }
    }
    __syncthreads();
    if (tid < 13 && dbase + tid < DM) {
        float D = 0.f;
        for (int t = 0; t < SEQ; ++t) {
            D += sDD[t][2 * tid];
            const float E = __expf(a * D);
            sE[t][tid] = E;
            sV[tid][t] = sDD[t][2 * tid + 1] / E;
        }
    }
    __syncthreads();
    for (int o = tid; o < 819; o += 256) {
        const int t = o / 13, dd = o - t * 13;
        if (dbase + dd >= DM) continue;
        const int lim = t + 1, q = lim & ~3;
        float acc = 0.f;
        int s = 0;
        for (; s < q; s += 4) {
            const float4 g = *(const float4*)&sG[t][s];
            const float4 v = *(const float4*)&sV[dd][s];
            acc += g.x * v.x + g.y * v.y + g.z * v.z + g.w * v.w;
        }
        for (; s < lim; ++s) acc += sG[t][s] * sV[dd][s];
        yT[(dbase + dd) * ROWS + b * SEQ + t] = sE[t][dd] * acc;
    }
}

// ---------------------------------------------------------------------------
// Fallback kernels (gated off when A uniform): R9 k_B + k_scan (row-major y).
// ---------------------------------------------------------------------------
template<bool ISB>
__device__ __forceinline__ float4 LD4(const void* p, int i) {
    if (ISB) {
        const uint2 u = ((const uint2*)p)[i];
        float4 r;
        r.x = __uint_as_float(u.x << 16);
        r.y = __uint_as_float(u.x & 0xffff0000u);
        r.z = __uint_as_float(u.y << 16);
        r.w = __uint_as_float(u.y & 0xffff0000u);
        return r;
    } else return ((const float4*)p)[i];
}

template<bool ISB>
__device__ __forceinline__ void b_impl(
    const float* __restrict__ t2g,
    const void* __restrict__ sW2, const void* __restrict__ sb2,
    const void* __restrict__ sW3, const void* __restrict__ sb3,
    float* __restrict__ BC, float (&sT)[DM][8])
{
    const int t  = threadIdx.x;
    const int r0 = blockIdx.x * 8;
    if (t < DM) {
#pragma unroll
        for (int r = 0; r < 8; ++r) sT[t][r] = t2g[(r0 + r) * DM + t];
    }
    __syncthreads();
    const bool isB = t < 75;
    const bool valid = t < 150;
    const int colbase = isB ? 4 * t : (valid ? 4 * (t - 75) : 0);
    const void* Wp   = isB ? sW2 : sW3;
    const void* bias = isB ? sb2 : sb3;
    const int rs4 = NS >> 2;
    const int cb4 = colbase >> 2;
    float4 acc[8];
    {
        const float4 bv = LD4<ISB>(bias, cb4);
#pragma unroll
        for (int r = 0; r < 8; ++r) acc[r] = bv;
    }
    float4 ring[4];
#pragma unroll
    for (int j = 0; j < 4; ++j) ring[j] = LD4<ISB>(Wp, j * rs4 + cb4);
    for (int kk = 0; kk < DM; kk += 4) {
#pragma unroll
        for (int j = 0; j < 4; ++j) {
            const int k = kk + j;
            const float4 wv = ring[j];
            if (k + 4 < DM) ring[j] = LD4<ISB>(Wp, (k + 4) * rs4 + cb4);
            const float4 lo = *(const float4*)&sT[k][0];
            const float4 hi = *(const float4*)&sT[k][4];
            acc[0].x += lo.x * wv.x; acc[0].y += lo.x * wv.y; acc[0].z += lo.x * wv.z; acc[0].w += lo.x * wv.w;
            acc[1].x += lo.y * wv.x; acc[1].y += lo.y * wv.y; acc[1].z += lo.y * wv.z; acc[1].w += lo.y * wv.w;
            acc[2].x += lo.z * wv.x; acc[2].y += lo.z * wv.y; acc[2].z += lo.z * wv.z; acc[2].w += lo.z * wv.w;
            acc[3].x += lo.w * wv.x; acc[3].y += lo.w * wv.y; acc[3].z += lo.w * wv.z; acc[3].w += lo.w * wv.w;
            acc[4].x += hi.x * wv.x; acc[4].y += hi.x * wv.y; acc[4].z += hi.x * wv.z; acc[4].w += hi.x * wv.w;
            acc[5].x += hi.y * wv.x; acc[5].y += hi.y * wv.y; acc[5].z += hi.y * wv.z; acc[5].w += hi.y * wv.w;
            acc[6].x += hi.z * wv.x; acc[6].y += hi.z * wv.y; acc[6].z += hi.z * wv.z; acc[6].w += hi.z * wv.w;
            acc[7].x += hi.w * wv.x; acc[7].y += hi.w * wv.y; acc[7].z += hi.w * wv.z; acc[7].w += hi.w * wv.w;
        }
    }
    if (valid) {
        const int off = isB ? 0 : 1;
#pragma unroll
        for (int r = 0; r < 8; ++r) {
            float* bp = BC + (r0 + r) * (2 * NS) + 2 * colbase + off;
            bp[0] = acc[r].x; bp[2] = acc[r].y;
            bp[4] = acc[r].z; bp[6] = acc[r].w;
        }
    }
}

__global__ __launch_bounds__(192, 1) void k_B(
    const float* t2g, const void* sW2, const void* sb2,
    const void* sW3, const void* sb3, float* BC,
    const float* Afl, const unsigned short* probe)
{
    __shared__ __align__(16) float sT[DM][8];
    if (flags_uniform(Afl)) return;
    if (detect_bf16(probe)) b_impl<true >(t2g, sW2, sb2, sW3, sb3, BC, sT);
    else                    b_impl<false>(t2g, sW2, sb2, sW3, sb3, BC, sT);
}

template<bool ISB>
__device__ __forceinline__ void scan_impl(
    const float* __restrict__ ddx, const float* __restrict__ BC,
    const void* __restrict__ sA, float* __restrict__ y,
    float (&sacc)[4][16][2][68])
{
    const int w    = threadIdx.x >> 6;
    const int lane = threadIdx.x & 63;
    const int wid  = blockIdx.x * 4 + w;
    const int b    = wid / 50;
    const int dp   = wid % 50;
    const int d0   = 2 * dp, d1 = d0 + 1;

    int nc[5]; bool nv[5];
    float A0[5], A1[5], h0[5], h1[5];
#pragma unroll
    for (int c = 0; c < 5; ++c) {
        const int n = lane + 64 * c;
        nv[c] = n < NS;
        nc[c] = nv[c] ? n : 0;
        A0[c] = nv[c] ? LD<ISB>(sA, d0 * NS + nc[c]) : 0.f;
        A1[c] = nv[c] ? LD<ISB>(sA, d1 * NS + nc[c]) : 0.f;
        h0[c] = 0.f; h1[c] = 0.f;
    }
    const float* ddp = ddx + (b * SEQ) * (2 * DM) + 4 * dp;
    const float* BCp = BC  + (b * SEQ) * (2 * NS);
    float*       yp  = y   + (b * SEQ) * DM + d0;

    float4 pdd[3];
    float2 pbc[3][5];
#pragma unroll
    for (int j = 0; j < 3; ++j) {
        pdd[j] = *(const float4*)(ddp + j * (2 * DM));
#pragma unroll
        for (int c = 0; c < 5; ++c)
            pbc[j][c] = nv[c] ? *(const float2*)(BCp + j * (2 * NS) + 2 * nc[c])
                              : make_float2(0.f, 0.f);
    }
    const int pr = lane >> 1;
    const int hh = lane & 1;
    const int sa = pr & 15;
    const int aa = pr >> 4;

#pragma unroll 3
    for (int l = 0; l < SEQ; ++l) {
        const int bi = l % 3;
        const float4 dd = pdd[bi];
        float2 bc[5];
#pragma unroll
        for (int c = 0; c < 5; ++c) bc[c] = pbc[bi][c];
        if (l + 3 < SEQ) {
            pdd[bi] = *(const float4*)(ddp + (l + 3) * (2 * DM));
#pragma unroll
            for (int c = 0; c < 5; ++c)
                pbc[bi][c] = nv[c] ? *(const float2*)(BCp + (l + 3) * (2 * NS) + 2 * nc[c])
                                   : make_float2(0.f, 0.f);
        }
        float a0 = 0.f, a1 = 0.f;
#pragma unroll
        for (int c = 0; c < 5; ++c) {
            h0[c] = __expf(dd.x * A0[c]) * h0[c] + dd.y * bc[c].x;
            a0 += bc[c].y * h0[c];
            h1[c] = __expf(dd.z * A1[c]) * h1[c] + dd.w * bc[c].x;
            a1 += bc[c].y * h1[c];
        }
        const int s = l & 15;
        sacc[w][s][0][lane] = a0;
        sacc[w][s][1][lane] = a1;

        if (s == 15 || l == SEQ - 1) {
            const int l0 = l & ~15;
            const int cs = l - l0 + 1;
            float sum = 0.f;
            if (sa < cs) {
                const float* rowp = &sacc[w][sa][aa][hh * 32];
#pragma unroll
                for (int i = 0; i < 8; ++i) {
                    const float4 v = *(const float4*)(rowp + 4 * i);
                    sum += v.x + v.y + v.z + v.w;
                }
            }
            sum += __shfl_xor(sum, 1, 64);
            if (hh == 0 && sa < cs) yp[(l0 + sa) * DM + aa] = sum;
        }
    }
}

__global__ __launch_bounds__(256) void k_scan(
    const float* ddx, const float* BC, const void* sA, float* y,
    const float* Afl, const unsigned short* probe)
{
    __shared__ __align__(16) float sacc[4][16][2][68];
    if (flags_uniform(Afl)) return;
    if (detect_bf16(probe)) scan_impl<true >(ddx, BC, sA, y, sacc);
    else                    scan_impl<false>(ddx, BC, sA, y, sacc);
}

// ---------------------------------------------------------------------------
// k_head: out[row] = y[row] @ M + k. Thread per row. Fast path reads yT
// (coalesced: consecutive threads = consecutive rows); fallback row-major.
// ---------------------------------------------------------------------------
template<bool ISB>
__device__ __forceinline__ void head_impl(
    const float* __restrict__ y, const float* __restrict__ Mkv,
    void* __restrict__ outp, bool fast)
{
    const int row = blockIdx.x * 256 + threadIdx.x;
    if (row >= ROWS) return;
    float a0 = Mkv[200], a1 = Mkv[201];
    if (fast) {
#pragma unroll 4
        for (int k = 0; k < DM; ++k) {
            const float v = y[k * ROWS + row];
            const float2 m = *(const float2*)(Mkv + 2 * k);
            a0 += v * m.x;
            a1 += v * m.y;
        }
    } else {
        const float* yr = y + row * DM;
#pragma unroll 4
        for (int k = 0; k < DM; ++k) {
            const float v = yr[k];
            const float2 m = *(const float2*)(Mkv + 2 * k);
            a0 += v * m.x;
            a1 += v * m.y;
        }
    }
    if (ISB) {
        ((bf16*)outp)[row * 2 + 0] = __float2bfloat16(a0);
        ((bf16*)outp)[row * 2 + 1] = __float2bfloat16(a1);
    } else {
        *(float2*)((float*)outp + row * 2) = make_float2(a0, a1);
    }
}

__global__ __launch_bounds__(256) void k_head(
    const float* y, const float* Mkv, void* outp,
    const float* Afl, const unsigned short* probe)
{
    const bool fast = flags_uniform(Afl);
    if (detect_bf16(probe)) head_impl<true >(y, Mkv, outp, fast);
    else                    head_impl<false>(y, Mkv, outp, fast);
}

// ---------------------------------------------------------------------------
extern "C" void kernel_launch(void* const* d_in, const int* in_sizes, int n_in,
                              void* d_out, int out_size, void* d_ws, size_t ws_size,
                              hipStream_t stream)
{
    const void* text = d_in[0];
    const void* tW1  = d_in[3];
    const void* tb1  = d_in[4];
    const void* tg1  = d_in[5];
    const void* tbe1 = d_in[6];
    const void* tW2  = d_in[7];
    const void* tb2  = d_in[8];
    const void* tg2  = d_in[9];
    const void* tbe2 = d_in[10];
    const void* sW1  = d_in[11];
    const void* sb1  = d_in[12];
    const void* sW2  = d_in[13];
    const void* sb2  = d_in[14];
    const void* sW3  = d_in[15];
    const void* sb3  = d_in[16];
    const void* sA   = d_in[17];
    const void* cW1  = d_in[34];
    const void* cb1  = d_in[35];
    const void* cW2  = d_in[36];
    const void* cb2  = d_in[37];
    const unsigned short* probe = (const unsigned short*)d_in[3];

    float* ws   = (float*)d_ws;
    float* ddx  = ws;                         // ROWS*200
    float* BCv  = ddx + ROWS * 2 * DM;        // ROWS*600 (fallback BC)
    float* Gv   = BCv;                        // alias: 64*3969 fast-path G
    float* yv   = BCv + ROWS * 2 * NS;        // ROWS*100 (t2g, then y/yT)
    float* Mkv  = yv + ROWS * DM;             // 202
    float* M33p = Mkv + 202;                  // 100*102
    float* k0w  = M33p + 10200;               // 1
    float* Afl  = k0w + 1;                    // 9 (8 flags + a)
    float* t2g  = yv;                         // alias: consumed before y write

    k_A<<<613, 256, 0, stream>>>(
        text, tW1, tb1, tg1, tbe1, tW2, tb2, tg2, tbe2,
        sW1, sb1, sW2, sb2, sW3, sb3, sA,
        cW1, cb1, cW2, cb2,
        ddx, t2g, Mkv, M33p, k0w, Afl, probe);

    k_B<<<ROWS / 8, 192, 0, stream>>>(t2g, sW2, sb2, sW3, sb3, BCv, Afl, probe);

    k_G<<<BATCH * 8, 256, 0, stream>>>(t2g, M33p, k0w, Gv, Afl);

    k_Y<<<BATCH * 8, 256, 0, stream>>>(ddx, Gv, yv, Afl);

    k_scan<<<3200 / 4, 256, 0, stream>>>(ddx, BCv, sA, yv, Afl, probe);

    k_head<<<(ROWS + 255) / 256, 256, 0, stream>>>(yv, Mkv, d_out, Afl, probe);
}